// Round 1
// baseline (13009.756 us; speedup 1.0000x reference)
//
#include <hip/hip_runtime.h>

// AbstractODEDecoder: unique-time grid + dopri5 latent ODE + fused MLP decoder.
// B=512, N=200, ZD=256, LD=128, HD=512, T=100, K=101.

typedef unsigned short u16;
typedef float f32x4 __attribute__((ext_vector_type(4)));
typedef short bf16x8 __attribute__((ext_vector_type(8)));
typedef u16 u16x8 __attribute__((ext_vector_type(8)));

#define MFMA16(a, b, c) __builtin_amdgcn_mfma_f32_16x16x32_bf16((a), (b), (c), 0, 0, 0)

constexpr int CB = 512;
constexpr int CN = 200;
constexpr int CZD = 256;
constexpr int CLD = 128;
constexpr int CHD = 512;
constexpr int CK = 101;
constexpr int CSTEPS = 100;

__device__ __forceinline__ u16 f2bf(float f) {
  unsigned u = __builtin_bit_cast(unsigned, f);
  u = (u + 0x7FFFu + ((u >> 16) & 1u)) >> 16;  // round-to-nearest-even bf16
  return (u16)u;
}

__device__ __forceinline__ f32x4 splat4(float v) {
  f32x4 r; r[0] = v; r[1] = v; r[2] = v; r[3] = v; return r;
}

// ---------------------------------------------------------------------------
// Kernel 1: unique-time grid (presence bitmap -> sorted times + rank)
// ---------------------------------------------------------------------------
__global__ void build_times_kernel(const float* __restrict__ x, const float* __restrict__ t0p,
                                   float* __restrict__ times, int* __restrict__ rank) {
  __shared__ int pres[128];
  const int tid = threadIdx.x;
  if (tid < 128) pres[tid] = 0;
  __syncthreads();
  for (int i = tid; i < CB * CN; i += blockDim.x) {
    float v = x[i];
    int gi = (int)(v * 100.0f + 0.5f);
    gi = gi < 0 ? 0 : (gi > 100 ? 100 : gi);
    pres[gi] = 1;
  }
  if (tid == 0) {
    float t0 = t0p[0];
    int gi = (int)(t0 * 100.0f + 0.5f);
    gi = gi < 0 ? 0 : (gi > 100 ? 100 : gi);
    pres[gi] = 1;
  }
  __syncthreads();
  if (tid == 0) {
    int c = 0;
    for (int i = 0; i <= 100; i++) {
      if (pres[i]) { times[c] = (float)i / 100.0f; rank[i] = c; c++; }
      else rank[i] = -1;
    }
    for (int j = c; j < CK; j++) times[j] = 1.0f;  // fill_value=1.0
  }
}

// ---------------------------------------------------------------------------
// Kernel 2: weight prep — bf16 transposed (B-fragment friendly) layouts.
// oWt1[n][k] (pitch 288): k<257 -> ode_W1[k][n] else 0       (k order: vL|z_hi|t)
// dWt1[n][k] (pitch 288): k<256 -> dec_W1[k+1][n]; k==256 -> dec_W1[0][n]; else 0
//                         (k order permuted to: latent|z_hi|x)
// ---------------------------------------------------------------------------
__global__ void prep_kernel(
    const float* __restrict__ oW1, const float* __restrict__ oW2, const float* __restrict__ oW3,
    const float* __restrict__ dW1, const float* __restrict__ dW2, const float* __restrict__ dW3,
    const float* __restrict__ z,
    u16* __restrict__ oWt1, u16* __restrict__ oWt2, u16* __restrict__ oWt3,
    u16* __restrict__ dWt1, u16* __restrict__ dWt2, u16* __restrict__ dWt3,
    u16* __restrict__ zbf) {
  const int tid = blockIdx.x * blockDim.x + threadIdx.x;
  const int nth = gridDim.x * blockDim.x;
  for (int i = tid; i < 512 * 288; i += nth) {
    int n = i / 288, k = i - n * 288;
    oWt1[i] = (k < 257) ? f2bf(oW1[k * 512 + n]) : (u16)0;
  }
  for (int i = tid; i < 512 * 512; i += nth) {
    int n = i >> 9, k = i & 511;
    oWt2[i] = f2bf(oW2[k * 512 + n]);
  }
  for (int i = tid; i < 128 * 512; i += nth) {
    int n = i >> 9, k = i & 511;
    oWt3[i] = f2bf(oW3[k * 128 + n]);
  }
  for (int i = tid; i < 512 * 288; i += nth) {
    int n = i / 288, k = i - n * 288;
    dWt1[i] = (k < 256) ? f2bf(dW1[(k + 1) * 512 + n])
                        : (k == 256 ? f2bf(dW1[n]) : (u16)0);
  }
  for (int i = tid; i < 512 * 512; i += nth) {
    int n = i >> 9, k = i & 511;
    dWt2[i] = f2bf(dW2[k * 512 + n]);
  }
  for (int i = tid; i < 512 * 512; i += nth) {
    int n = i >> 9, k = i & 511;
    dWt3[i] = f2bf(dW3[k * 512 + n]);
  }
  for (int i = tid; i < 512 * 128; i += nth) {
    int b = i >> 7, d = i & 127;
    zbf[i] = f2bf(z[b * 256 + 128 + d]);
  }
}

// ---------------------------------------------------------------------------
// Kernel 3: ODE integrate. 32 blocks x 1024 threads (16 waves), 16 batch rows
// per block, all weights resident in VGPRs, activations in LDS frag-layout.
// vhist[k][b][0:128] written for k = 0..100.
// ---------------------------------------------------------------------------
__global__ __launch_bounds__(1024) void ode_kernel(
    const float* __restrict__ z,
    const u16* __restrict__ Wt1, const u16* __restrict__ Wt2, const u16* __restrict__ Wt3,
    const float* __restrict__ b1, const float* __restrict__ b2, const float* __restrict__ b3,
    const float* __restrict__ times, float* __restrict__ vhist) {
  __shared__ __align__(16) u16 aF[9][64][8];    // A-tile fragments (K = 288)
  __shared__ __align__(16) u16 h1F[16][64][8];  // h1 fragments (K = 512)
  __shared__ __align__(16) u16 h2F[16][64][8];  // h2 fragments
  __shared__ float kb[6][16][132];              // k1..k6, padded pitch
  __shared__ float ts[112];

  const int tid = threadIdx.x;
  const int lane = tid & 63;
  const int wave = tid >> 6;
  const int r0 = blockIdx.x * 16;
  const int m_ = tid & 15;         // row this thread owns in elementwise phases
  const int d_ = (tid >> 4) << 1;  // dim pair (0,2,...,126)
  const int colq = lane & 15;
  const int gq = lane >> 4;

  if (tid < CK) ts[tid] = times[tid];

  // evolving state for (m_, d_), (m_, d_+1) lives in registers
  float v0 = z[(r0 + m_) * CZD + d_];
  float v1 = z[(r0 + m_) * CZD + d_ + 1];
  {
    float2 vv; vv.x = v0; vv.y = v1;
    *(float2*)&vhist[(0 * CB + r0 + m_) * CLD + d_] = vv;
  }
  {  // constant z_hi half of the A-tile (chunks 4..7), written once
    float z0 = z[(r0 + m_) * CZD + 128 + d_];
    float z1 = z[(r0 + m_) * CZD + 128 + d_ + 1];
    int k = 128 + d_;
    int c = k >> 5, gh = (k & 31) >> 3, sl = k & 7;
    unsigned pk = (unsigned)f2bf(z0) | ((unsigned)f2bf(z1) << 16);
    *(unsigned*)&aF[c][m_ + gh * 16][sl] = pk;
  }
  if (tid < 512) ((u16*)aF[8])[tid] = 0;  // t chunk: zeros except per-eval t slot

  // ---- weights into registers: wave owns cols [wave*32, wave*32+32) ----
  bf16x8 w1f[9][2], w2f[16][2], w3f[16];
  {
    const int nb = wave * 32;
#pragma unroll
    for (int c = 0; c < 9; c++) {
      w1f[c][0] = *(const bf16x8*)&Wt1[(nb + colq) * 288 + c * 32 + gq * 8];
      w1f[c][1] = *(const bf16x8*)&Wt1[(nb + 16 + colq) * 288 + c * 32 + gq * 8];
    }
#pragma unroll
    for (int c = 0; c < 16; c++) {
      w2f[c][0] = *(const bf16x8*)&Wt2[(nb + colq) * 512 + c * 32 + gq * 8];
      w2f[c][1] = *(const bf16x8*)&Wt2[(nb + 16 + colq) * 512 + c * 32 + gq * 8];
    }
    if (wave < 8) {
#pragma unroll
      for (int c = 0; c < 16; c++)
        w3f[c] = *(const bf16x8*)&Wt3[(wave * 16 + colq) * 512 + c * 32 + gq * 8];
    }
  }
  const float b1v0 = b1[wave * 32 + colq], b1v1 = b1[wave * 32 + 16 + colq];
  const float b2v0 = b2[wave * 32 + colq], b2v1 = b2[wave * 32 + 16 + colq];
  const float b3v = (wave < 8) ? b3[wave * 16 + colq] : 0.0f;
  __syncthreads();

  auto eval = [&](float vin0, float vin1, float tstage, int kout) {
    {  // write A chunks 0..3 (evolving part) + t slot
      int c = d_ >> 5, gh = (d_ & 31) >> 3, sl = d_ & 7;
      unsigned pk = (unsigned)f2bf(vin0) | ((unsigned)f2bf(vin1) << 16);
      *(unsigned*)&aF[c][m_ + gh * 16][sl] = pk;
      if (tid < 16) aF[8][tid][0] = f2bf(tstage);
    }
    __syncthreads();
    // ---- L1: h1 = tanh(vt @ W1 + b1) ----
    f32x4 acc0 = splat4(b1v0);
    f32x4 acc1 = splat4(b1v1);
#pragma unroll
    for (int c = 0; c < 9; c++) {
      bf16x8 af = *(const bf16x8*)&aF[c][lane][0];
      acc0 = MFMA16(af, w1f[c][0], acc0);
      acc1 = MFMA16(af, w1f[c][1], acc1);
    }
#pragma unroll
    for (int t = 0; t < 2; t++) {
      int col = wave * 32 + t * 16 + colq;
      int cc = col >> 5, gh = (col & 31) >> 3, sl = col & 7;
      f32x4 a = t ? acc1 : acc0;
#pragma unroll
      for (int r = 0; r < 4; r++)
        h1F[cc][gq * 4 + r + gh * 16][sl] = f2bf(tanhf(a[r]));
    }
    __syncthreads();
    // ---- L2: h2 = tanh(h1 @ W2 + b2) ----
    acc0 = splat4(b2v0);
    acc1 = splat4(b2v1);
#pragma unroll
    for (int c = 0; c < 16; c++) {
      bf16x8 hf = *(const bf16x8*)&h1F[c][lane][0];
      acc0 = MFMA16(hf, w2f[c][0], acc0);
      acc1 = MFMA16(hf, w2f[c][1], acc1);
    }
#pragma unroll
    for (int t = 0; t < 2; t++) {
      int col = wave * 32 + t * 16 + colq;
      int cc = col >> 5, gh = (col & 31) >> 3, sl = col & 7;
      f32x4 a = t ? acc1 : acc0;
#pragma unroll
      for (int r = 0; r < 4; r++)
        h2F[cc][gq * 4 + r + gh * 16][sl] = f2bf(tanhf(a[r]));
    }
    __syncthreads();
    // ---- L3: dL = h2 @ W3 + b3 (waves 0..7 own 16 cols each) ----
    if (wave < 8) {
      f32x4 acc = splat4(b3v);
#pragma unroll
      for (int c = 0; c < 16; c++) {
        bf16x8 hf = *(const bf16x8*)&h2F[c][lane][0];
        acc = MFMA16(hf, w3f[c], acc);
      }
      int col = wave * 16 + colq;
#pragma unroll
      for (int r = 0; r < 4; r++)
        kb[kout][gq * 4 + r][col] = acc[r];
    }
    __syncthreads();
  };

#pragma unroll 1
  for (int s = 0; s < CSTEPS; s++) {
    const float t0s = ts[s], t1s = ts[s + 1];
    const float dt = t1s - t0s;

    eval(v0, v1, t0s, 0);
    float k1a = kb[0][m_][d_], k1b = kb[0][m_][d_ + 1];
    eval(v0 + dt * 0.2f * k1a, v1 + dt * 0.2f * k1b, t0s + 0.2f * dt, 1);
    float k2a = kb[1][m_][d_], k2b = kb[1][m_][d_ + 1];
    eval(v0 + dt * ((float)(3.0 / 40.0) * k1a + (float)(9.0 / 40.0) * k2a),
         v1 + dt * ((float)(3.0 / 40.0) * k1b + (float)(9.0 / 40.0) * k2b),
         t0s + 0.3f * dt, 2);
    float k3a = kb[2][m_][d_], k3b = kb[2][m_][d_ + 1];
    eval(v0 + dt * ((float)(44.0 / 45.0) * k1a - (float)(56.0 / 15.0) * k2a + (float)(32.0 / 9.0) * k3a),
         v1 + dt * ((float)(44.0 / 45.0) * k1b - (float)(56.0 / 15.0) * k2b + (float)(32.0 / 9.0) * k3b),
         t0s + 0.8f * dt, 3);
    float k4a = kb[3][m_][d_], k4b = kb[3][m_][d_ + 1];
    eval(v0 + dt * ((float)(19372.0 / 6561.0) * k1a - (float)(25360.0 / 2187.0) * k2a +
                    (float)(64448.0 / 6561.0) * k3a - (float)(212.0 / 729.0) * k4a),
         v1 + dt * ((float)(19372.0 / 6561.0) * k1b - (float)(25360.0 / 2187.0) * k2b +
                    (float)(64448.0 / 6561.0) * k3b - (float)(212.0 / 729.0) * k4b),
         t0s + (float)(8.0 / 9.0) * dt, 4);
    float k5a = kb[4][m_][d_], k5b = kb[4][m_][d_ + 1];
    eval(v0 + dt * ((float)(9017.0 / 3168.0) * k1a - (float)(355.0 / 33.0) * k2a +
                    (float)(46732.0 / 5247.0) * k3a + (float)(49.0 / 176.0) * k4a -
                    (float)(5103.0 / 18656.0) * k5a),
         v1 + dt * ((float)(9017.0 / 3168.0) * k1b - (float)(355.0 / 33.0) * k2b +
                    (float)(46732.0 / 5247.0) * k3b + (float)(49.0 / 176.0) * k4b -
                    (float)(5103.0 / 18656.0) * k5b),
         t0s + dt, 5);
    float k6a = kb[5][m_][d_], k6b = kb[5][m_][d_ + 1];

    v0 += dt * ((float)(35.0 / 384.0) * k1a + (float)(500.0 / 1113.0) * k3a +
                (float)(125.0 / 192.0) * k4a - (float)(2187.0 / 6784.0) * k5a +
                (float)(11.0 / 84.0) * k6a);
    v1 += dt * ((float)(35.0 / 384.0) * k1b + (float)(500.0 / 1113.0) * k3b +
                (float)(125.0 / 192.0) * k4b - (float)(2187.0 / 6784.0) * k5b +
                (float)(11.0 / 84.0) * k6b);

    float2 vv; vv.x = v0; vv.y = v1;
    *(float2*)&vhist[((s + 1) * CB + r0 + m_) * CLD + d_] = vv;
  }
}

// ---------------------------------------------------------------------------
// Kernel 4: fused decoder. 1600 blocks x 512 threads, 64 rows/block.
// A-tile K order: [latent(0..127) | z_hi(128..255) | x(256) | 0-pad].
// Wave w owns output cols [w*64, w*64+64). Gather of latent fused into build.
// ---------------------------------------------------------------------------
__global__ __launch_bounds__(512) void dec_kernel(
    const float* __restrict__ x, const u16* __restrict__ zbf,
    const float* __restrict__ vhist, const int* __restrict__ rank,
    const u16* __restrict__ Wt1, const u16* __restrict__ Wt2, const u16* __restrict__ Wt3,
    const float* __restrict__ b1, const float* __restrict__ b2, const float* __restrict__ b3,
    float* __restrict__ out) {
  __shared__ __align__(16) u16 hA[4][16][64][8];   // A (chunks 0..8), then h2
  __shared__ __align__(16) u16 h1F[4][16][64][8];  // h1
  __shared__ int rk[104];

  const int tid = threadIdx.x, lane = tid & 63, wave = tid >> 6;
  const int R0 = blockIdx.x * 64;

  if (tid < CK) rk[tid] = rank[tid];
  __syncthreads();

  {  // build A-tile (fused latent gather)
    const int i = tid >> 3, j = tid & 7;  // row-in-block, 1/8th of K-dims
    const int row = R0 + i;
    const int b = row / CN;
    const float xv = x[row];
    int gi = (int)(xv * 100.0f + 0.5f);
    gi = gi < 0 ? 0 : (gi > 100 ? 100 : gi);
    const int k = rk[gi];
    const int mt = i >> 4, m = i & 15;
    const float4* lp = (const float4*)&vhist[((k * CB) + b) * CLD + j * 16];
    float4 l0 = lp[0], l1 = lp[1], l2 = lp[2], l3 = lp[3];
    u16x8 lv0, lv1;
    lv0[0] = f2bf(l0.x); lv0[1] = f2bf(l0.y); lv0[2] = f2bf(l0.z); lv0[3] = f2bf(l0.w);
    lv0[4] = f2bf(l1.x); lv0[5] = f2bf(l1.y); lv0[6] = f2bf(l1.z); lv0[7] = f2bf(l1.w);
    lv1[0] = f2bf(l2.x); lv1[1] = f2bf(l2.y); lv1[2] = f2bf(l2.z); lv1[3] = f2bf(l2.w);
    lv1[4] = f2bf(l3.x); lv1[5] = f2bf(l3.y); lv1[6] = f2bf(l3.z); lv1[7] = f2bf(l3.w);
    const int c = j >> 1, gh = (j & 1) * 2;
    *(u16x8*)&hA[mt][c][m + gh * 16][0] = lv0;
    *(u16x8*)&hA[mt][c][m + (gh + 1) * 16][0] = lv1;
    const u16x8* zp = (const u16x8*)&zbf[b * CLD + j * 16];
    u16x8 zv0 = zp[0], zv1 = zp[1];
    *(u16x8*)&hA[mt][4 + c][m + gh * 16][0] = zv0;
    *(u16x8*)&hA[mt][4 + c][m + (gh + 1) * 16][0] = zv1;
    if (j == 0) {
      hA[mt][8][m][0] = f2bf(xv);
#pragma unroll
      for (int q = 1; q < 8; q++) hA[mt][8][m][q] = 0;
    } else if (j < 4) {
      u16x8 zz = {0, 0, 0, 0, 0, 0, 0, 0};
      *(u16x8*)&hA[mt][8][m + j * 16][0] = zz;
    }
  }
  __syncthreads();

  const int colq = lane & 15, gq = lane >> 4;
  const int nb = wave * 64;
  f32x4 acc[4][4];

  // ---- L1 ----
#pragma unroll
  for (int nt = 0; nt < 4; nt++) {
    float bv = b1[nb + nt * 16 + colq];
#pragma unroll
    for (int mt = 0; mt < 4; mt++) acc[mt][nt] = splat4(bv);
  }
#pragma unroll
  for (int c = 0; c < 9; c++) {
    bf16x8 af0 = *(const bf16x8*)&hA[0][c][lane][0];
    bf16x8 af1 = *(const bf16x8*)&hA[1][c][lane][0];
    bf16x8 af2 = *(const bf16x8*)&hA[2][c][lane][0];
    bf16x8 af3 = *(const bf16x8*)&hA[3][c][lane][0];
#pragma unroll
    for (int nt = 0; nt < 4; nt++) {
      bf16x8 bfv = *(const bf16x8*)&Wt1[(size_t)(nb + nt * 16 + colq) * 288 + c * 32 + gq * 8];
      acc[0][nt] = MFMA16(af0, bfv, acc[0][nt]);
      acc[1][nt] = MFMA16(af1, bfv, acc[1][nt]);
      acc[2][nt] = MFMA16(af2, bfv, acc[2][nt]);
      acc[3][nt] = MFMA16(af3, bfv, acc[3][nt]);
    }
  }
#pragma unroll
  for (int mt = 0; mt < 4; mt++)
#pragma unroll
    for (int nt = 0; nt < 4; nt++) {
      int col = nb + nt * 16 + colq;
      int cc = col >> 5, gh = (col & 31) >> 3, sl = col & 7;
#pragma unroll
      for (int r = 0; r < 4; r++)
        h1F[mt][cc][gq * 4 + r + gh * 16][sl] = f2bf(fmaxf(acc[mt][nt][r], 0.0f));
    }
  __syncthreads();

  // ---- L2 ---- (h1F -> hA)
#pragma unroll
  for (int nt = 0; nt < 4; nt++) {
    float bv = b2[nb + nt * 16 + colq];
#pragma unroll
    for (int mt = 0; mt < 4; mt++) acc[mt][nt] = splat4(bv);
  }
#pragma unroll
  for (int c = 0; c < 16; c++) {
    bf16x8 af0 = *(const bf16x8*)&h1F[0][c][lane][0];
    bf16x8 af1 = *(const bf16x8*)&h1F[1][c][lane][0];
    bf16x8 af2 = *(const bf16x8*)&h1F[2][c][lane][0];
    bf16x8 af3 = *(const bf16x8*)&h1F[3][c][lane][0];
#pragma unroll
    for (int nt = 0; nt < 4; nt++) {
      bf16x8 bfv = *(const bf16x8*)&Wt2[(size_t)(nb + nt * 16 + colq) * 512 + c * 32 + gq * 8];
      acc[0][nt] = MFMA16(af0, bfv, acc[0][nt]);
      acc[1][nt] = MFMA16(af1, bfv, acc[1][nt]);
      acc[2][nt] = MFMA16(af2, bfv, acc[2][nt]);
      acc[3][nt] = MFMA16(af3, bfv, acc[3][nt]);
    }
  }
#pragma unroll
  for (int mt = 0; mt < 4; mt++)
#pragma unroll
    for (int nt = 0; nt < 4; nt++) {
      int col = nb + nt * 16 + colq;
      int cc = col >> 5, gh = (col & 31) >> 3, sl = col & 7;
#pragma unroll
      for (int r = 0; r < 4; r++)
        hA[mt][cc][gq * 4 + r + gh * 16][sl] = f2bf(fmaxf(acc[mt][nt][r], 0.0f));
    }
  __syncthreads();

  // ---- L3 ---- (hA -> out)
#pragma unroll
  for (int nt = 0; nt < 4; nt++) {
    float bv = b3[nb + nt * 16 + colq];
#pragma unroll
    for (int mt = 0; mt < 4; mt++) acc[mt][nt] = splat4(bv);
  }
#pragma unroll
  for (int c = 0; c < 16; c++) {
    bf16x8 af0 = *(const bf16x8*)&hA[0][c][lane][0];
    bf16x8 af1 = *(const bf16x8*)&hA[1][c][lane][0];
    bf16x8 af2 = *(const bf16x8*)&hA[2][c][lane][0];
    bf16x8 af3 = *(const bf16x8*)&hA[3][c][lane][0];
#pragma unroll
    for (int nt = 0; nt < 4; nt++) {
      bf16x8 bfv = *(const bf16x8*)&Wt3[(size_t)(nb + nt * 16 + colq) * 512 + c * 32 + gq * 8];
      acc[0][nt] = MFMA16(af0, bfv, acc[0][nt]);
      acc[1][nt] = MFMA16(af1, bfv, acc[1][nt]);
      acc[2][nt] = MFMA16(af2, bfv, acc[2][nt]);
      acc[3][nt] = MFMA16(af3, bfv, acc[3][nt]);
    }
  }
#pragma unroll
  for (int mt = 0; mt < 4; mt++)
#pragma unroll
    for (int nt = 0; nt < 4; nt++) {
      int col = nb + nt * 16 + colq;
#pragma unroll
      for (int r = 0; r < 4; r++) {
        int row = R0 + mt * 16 + gq * 4 + r;
        out[(size_t)row * CHD + col] = fmaxf(acc[mt][nt][r], 0.0f);
      }
    }
}

// ---------------------------------------------------------------------------
extern "C" void kernel_launch(void* const* d_in, const int* in_sizes, int n_in,
                              void* d_out, int out_size, void* d_ws, size_t ws_size,
                              hipStream_t stream) {
  (void)in_sizes; (void)n_in; (void)out_size; (void)ws_size;

  const float* x   = (const float*)d_in[0];
  const float* z   = (const float*)d_in[1];
  const float* t0  = (const float*)d_in[2];
  const float* oW1 = (const float*)d_in[3];
  const float* ob1 = (const float*)d_in[4];
  const float* oW2 = (const float*)d_in[5];
  const float* ob2 = (const float*)d_in[6];
  const float* oW3 = (const float*)d_in[7];
  const float* ob3 = (const float*)d_in[8];
  const float* dW1 = (const float*)d_in[9];
  const float* db1 = (const float*)d_in[10];
  const float* dW2 = (const float*)d_in[11];
  const float* db2 = (const float*)d_in[12];
  const float* dW3 = (const float*)d_in[13];
  const float* db3 = (const float*)d_in[14];

  char* ws = (char*)d_ws;
  size_t off = 0;
  auto alloc = [&](size_t bytes) {
    void* p = ws + off;
    off = (off + bytes + 255) & ~(size_t)255;
    return p;
  };
  float* vhist = (float*)alloc((size_t)CK * CB * CLD * 4);   // 26.5 MB
  u16* oWt1 = (u16*)alloc(512 * 288 * 2);
  u16* oWt2 = (u16*)alloc(512 * 512 * 2);
  u16* oWt3 = (u16*)alloc(128 * 512 * 2);
  u16* dWt1 = (u16*)alloc(512 * 288 * 2);
  u16* dWt2 = (u16*)alloc(512 * 512 * 2);
  u16* dWt3 = (u16*)alloc(512 * 512 * 2);
  u16* zbf  = (u16*)alloc(512 * 128 * 2);
  float* times = (float*)alloc(512);
  int* rank    = (int*)alloc(512);

  build_times_kernel<<<dim3(1), dim3(256), 0, stream>>>(x, t0, times, rank);
  prep_kernel<<<dim3(512), dim3(256), 0, stream>>>(oW1, oW2, oW3, dW1, dW2, dW3, z,
                                                   oWt1, oWt2, oWt3, dWt1, dWt2, dWt3, zbf);
  ode_kernel<<<dim3(32), dim3(1024), 0, stream>>>(z, oWt1, oWt2, oWt3, ob1, ob2, ob3,
                                                  times, vhist);
  dec_kernel<<<dim3(1600), dim3(512), 0, stream>>>(x, zbf, vhist, rank,
                                                   dWt1, dWt2, dWt3, db1, db2, db3,
                                                   (float*)d_out);
}

// Round 2
// 6084.483 us; speedup vs baseline: 2.1382x; 2.1382x over previous
//
#include <hip/hip_runtime.h>

// AbstractODEDecoder: unique-time grid + RK4 latent ODE + fused MLP decoder.
// B=512, N=200, ZD=256, LD=128, HD=512, T=100, K=101.

typedef unsigned short u16;
typedef float f32x4 __attribute__((ext_vector_type(4)));
typedef short bf16x8 __attribute__((ext_vector_type(8)));
typedef u16 u16x8 __attribute__((ext_vector_type(8)));

#define MFMA16(a, b, c) __builtin_amdgcn_mfma_f32_16x16x32_bf16((a), (b), (c), 0, 0, 0)

constexpr int CB = 512;
constexpr int CN = 200;
constexpr int CZD = 256;
constexpr int CLD = 128;
constexpr int CHD = 512;
constexpr int CK = 101;
constexpr int CSTEPS = 100;

__device__ __forceinline__ u16 f2bf(float f) {
  unsigned u = __builtin_bit_cast(unsigned, f);
  u = (u + 0x7FFFu + ((u >> 16) & 1u)) >> 16;  // round-to-nearest-even bf16
  return (u16)u;
}

__device__ __forceinline__ f32x4 splat4(float v) {
  f32x4 r; r[0] = v; r[1] = v; r[2] = v; r[3] = v; return r;
}

__device__ __forceinline__ float fast_tanh(float x) {
  float e = __expf(2.0f * x);
  return 1.0f - 2.0f / (e + 1.0f);
}

// ---------------------------------------------------------------------------
// Kernel 1: unique-time grid (presence bitmap -> sorted times + rank)
// ---------------------------------------------------------------------------
__global__ void build_times_kernel(const float* __restrict__ x, const float* __restrict__ t0p,
                                   float* __restrict__ times, int* __restrict__ rank) {
  __shared__ int pres[128];
  const int tid = threadIdx.x;
  if (tid < 128) pres[tid] = 0;
  __syncthreads();
  for (int i = tid; i < CB * CN; i += blockDim.x) {
    float v = x[i];
    int gi = (int)(v * 100.0f + 0.5f);
    gi = gi < 0 ? 0 : (gi > 100 ? 100 : gi);
    pres[gi] = 1;
  }
  if (tid == 0) {
    float t0 = t0p[0];
    int gi = (int)(t0 * 100.0f + 0.5f);
    gi = gi < 0 ? 0 : (gi > 100 ? 100 : gi);
    pres[gi] = 1;
  }
  __syncthreads();
  if (tid == 0) {
    int c = 0;
    for (int i = 0; i <= 100; i++) {
      if (pres[i]) { times[c] = (float)i / 100.0f; rank[i] = c; c++; }
      else rank[i] = -1;
    }
    for (int j = c; j < CK; j++) times[j] = 1.0f;  // fill_value=1.0
  }
}

// ---------------------------------------------------------------------------
// Kernel 2: weight prep.
// ODE weights in fragment-linear bf16 layout: element ((c*NT + tile)*64 + lane)*8 + j
//   holds W[k = c*32 + (lane>>4)*8 + j][n = tile*16 + (lane&15)].
//   W1f: ode_W1 rows 0..127 (evolving latent). W1hf: rows 128..255 (z_hi, for c_pre).
//   W2f: 16 chunks x 32 tiles. W3f: 16 chunks x 8 tiles (128 cols).
// Decoder weights keep the round-1 [n][k] layout (dWt1 K-order: latent|z_hi|x).
// ---------------------------------------------------------------------------
__global__ void prep_kernel(
    const float* __restrict__ oW1, const float* __restrict__ oW2, const float* __restrict__ oW3,
    const float* __restrict__ dW1, const float* __restrict__ dW2, const float* __restrict__ dW3,
    const float* __restrict__ z,
    u16* __restrict__ W1f, u16* __restrict__ W1hf, u16* __restrict__ W2f, u16* __restrict__ W3f,
    u16* __restrict__ dWt1, u16* __restrict__ dWt2, u16* __restrict__ dWt3,
    u16* __restrict__ zbf) {
  const int tid = blockIdx.x * blockDim.x + threadIdx.x;
  const int nth = gridDim.x * blockDim.x;
  // W1f / W1hf: 4 chunks x 32 tiles
  for (int i = tid; i < 65536; i += nth) {
    int j = i & 7, lane = (i >> 3) & 63, tc = i >> 9, tile = tc & 31, c = tc >> 5;
    int k = c * 32 + (lane >> 4) * 8 + j, n = tile * 16 + (lane & 15);
    W1f[i]  = f2bf(oW1[k * 512 + n]);
    W1hf[i] = f2bf(oW1[(128 + k) * 512 + n]);
  }
  // W2f: 16 chunks x 32 tiles
  for (int i = tid; i < 262144; i += nth) {
    int j = i & 7, lane = (i >> 3) & 63, tc = i >> 9, tile = tc & 31, c = tc >> 5;
    int k = c * 32 + (lane >> 4) * 8 + j, n = tile * 16 + (lane & 15);
    W2f[i] = f2bf(oW2[k * 512 + n]);
  }
  // W3f: 16 chunks x 8 tiles
  for (int i = tid; i < 65536; i += nth) {
    int j = i & 7, lane = (i >> 3) & 63, tc = i >> 9, tile = tc & 7, c = tc >> 3;
    int k = c * 32 + (lane >> 4) * 8 + j, n = tile * 16 + (lane & 15);
    W3f[i] = f2bf(oW3[k * 128 + n]);
  }
  // decoder weights (round-1 layouts, verified)
  for (int i = tid; i < 512 * 288; i += nth) {
    int n = i / 288, k = i - n * 288;
    dWt1[i] = (k < 256) ? f2bf(dW1[(k + 1) * 512 + n])
                        : (k == 256 ? f2bf(dW1[n]) : (u16)0);
  }
  for (int i = tid; i < 512 * 512; i += nth) {
    int n = i >> 9, k = i & 511;
    dWt2[i] = f2bf(dW2[k * 512 + n]);
  }
  for (int i = tid; i < 512 * 512; i += nth) {
    int n = i >> 9, k = i & 511;
    dWt3[i] = f2bf(dW3[k * 512 + n]);
  }
  for (int i = tid; i < 512 * 128; i += nth) {
    int b = i >> 7, d = i & 127;
    zbf[i] = f2bf(z[b * 256 + 128 + d]);
  }
}

// ---------------------------------------------------------------------------
// Kernel 3: RK4 ODE integrate. 32 blocks x 512 threads (8 waves), 16 rows/block.
// Resident: W1 (vL part) + W3 in VGPRs, W2 chunks 0..2 in LDS; W2 chunks 3..15
// streamed from L2 (double-buffered regs). z_hi folded into c_pre acc-init;
// t handled as f32 rank-1 update. State/k's live in the L3 C-fragment layout
// (thread owns v[gq*4+r][wave*16+colq]) -> zero LDS for RK combinations.
// ---------------------------------------------------------------------------
__global__ __launch_bounds__(512, 2) void ode_kernel(
    const float* __restrict__ z,
    const u16* __restrict__ W1f, const u16* __restrict__ W1hf,
    const u16* __restrict__ W2f, const u16* __restrict__ W3f,
    const float* __restrict__ oW1,
    const float* __restrict__ b1, const float* __restrict__ b2, const float* __restrict__ b3,
    const float* __restrict__ times, float* __restrict__ vhist) {
  __shared__ __align__(16) u16 W2L[3 * 32 * 64 * 8];  // chunks 0..2, 98304 B
  __shared__ __align__(16) u16 aF[4][64][8];          // A fragments (K=128)
  __shared__ __align__(16) u16 h1F[16][64][8];        // h1 fragments
  __shared__ __align__(16) u16 h2F[16][64][8];        // h2 fragments

  const int tid = threadIdx.x, lane = tid & 63, wave = tid >> 6;
  const int colq = lane & 15, gq = lane >> 4;
  const int r0 = blockIdx.x * 16;
  const int d_ = wave * 16 + colq;  // state column this thread owns

  // stage W2 chunks 0..2 into LDS (layout identical to W2f head)
  for (int i = tid; i < 6144; i += 512)
    *(u16x8*)&W2L[i * 8] = *(const u16x8*)&W2f[i * 8];

  // resident weight fragments
  bf16x8 w1f[4][4];
#pragma unroll
  for (int c = 0; c < 4; c++)
#pragma unroll
    for (int t = 0; t < 4; t++)
      w1f[c][t] = *(const bf16x8*)&W1f[((c * 32 + wave * 4 + t) * 64 + lane) * 8];
  bf16x8 w3f[16];
#pragma unroll
  for (int c = 0; c < 16; c++)
    w3f[c] = *(const bf16x8*)&W3f[((c * 8 + wave) * 64 + lane) * 8];

  float b2v[4], wtv[4];
#pragma unroll
  for (int t = 0; t < 4; t++) {
    int col = wave * 64 + t * 16 + colq;
    b2v[t] = b2[col];
    wtv[t] = oW1[256 * 512 + col];  // t-row of ode_W1
  }
  const float b3v = b3[wave * 16 + colq];

  // state + vhist[0]
  f32x4 v;
#pragma unroll
  for (int r = 0; r < 4; r++) {
    v[r] = z[(r0 + gq * 4 + r) * CZD + d_];
    vhist[(0 * CB + r0 + gq * 4 + r) * CLD + d_] = v[r];
  }

  // --- c_pre = b1 + z_hi @ W1[128:256]  (constant across all evals) ---
  {
    int c = d_ >> 5, gh = (d_ & 31) >> 3, sl = d_ & 7;
#pragma unroll
    for (int r = 0; r < 4; r++)
      aF[c][gq * 4 + r + gh * 16][sl] = f2bf(z[(r0 + gq * 4 + r) * CZD + 128 + d_]);
  }
  __syncthreads();
  f32x4 cpre[4];
#pragma unroll
  for (int t = 0; t < 4; t++) cpre[t] = splat4(b1[wave * 64 + t * 16 + colq]);
#pragma unroll
  for (int c = 0; c < 4; c++) {
    bf16x8 af = *(const bf16x8*)&aF[c][lane][0];
#pragma unroll
    for (int t = 0; t < 4; t++)
      cpre[t] = MFMA16(af, *(const bf16x8*)&W1hf[((c * 32 + wave * 4 + t) * 64 + lane) * 8],
                       cpre[t]);
  }
  __syncthreads();

  auto eval = [&](f32x4 si, float tstage) -> f32x4 {
    // prefetch streamed W2 chunks 3,4 (independent of LDS state)
    bf16x8 sb[2][4];
#pragma unroll
    for (int t = 0; t < 4; t++) {
      sb[0][t] = *(const bf16x8*)&W2f[((3 * 32 + wave * 4 + t) * 64 + lane) * 8];
      sb[1][t] = *(const bf16x8*)&W2f[((4 * 32 + wave * 4 + t) * 64 + lane) * 8];
    }
    // write evolving-latent A fragments
    {
      int c = d_ >> 5, gh = (d_ & 31) >> 3, sl = d_ & 7;
#pragma unroll
      for (int r = 0; r < 4; r++)
        aF[c][gq * 4 + r + gh * 16][sl] = f2bf(si[r]);
    }
    __syncthreads();
    // ---- L1: h1 = tanh(cpre + t*wt + vL @ W1) ----
    f32x4 acc[4];
#pragma unroll
    for (int t = 0; t < 4; t++) {
      f32x4 a;
#pragma unroll
      for (int r = 0; r < 4; r++) a[r] = cpre[t][r] + tstage * wtv[t];
      acc[t] = a;
    }
#pragma unroll
    for (int c = 0; c < 4; c++) {
      bf16x8 af = *(const bf16x8*)&aF[c][lane][0];
#pragma unroll
      for (int t = 0; t < 4; t++) acc[t] = MFMA16(af, w1f[c][t], acc[t]);
    }
#pragma unroll
    for (int t = 0; t < 4; t++) {
      int col = wave * 64 + t * 16 + colq;
      int cc = col >> 5, gh = (col & 31) >> 3, sl = col & 7;
#pragma unroll
      for (int r = 0; r < 4; r++)
        h1F[cc][gq * 4 + r + gh * 16][sl] = f2bf(fast_tanh(acc[t][r]));
    }
    __syncthreads();
    // ---- L2: h2 = tanh(h1 @ W2 + b2); chunks 0..2 LDS, 3..15 streamed ----
#pragma unroll
    for (int t = 0; t < 4; t++) acc[t] = splat4(b2v[t]);
#pragma unroll
    for (int c = 0; c < 3; c++) {
      bf16x8 hf = *(const bf16x8*)&h1F[c][lane][0];
#pragma unroll
      for (int t = 0; t < 4; t++)
        acc[t] = MFMA16(hf, *(const bf16x8*)&W2L[((c * 32 + wave * 4 + t) * 64 + lane) * 8],
                        acc[t]);
    }
#pragma unroll
    for (int c = 3; c < 16; c++) {
      bf16x8 hf = *(const bf16x8*)&h1F[c][lane][0];
#pragma unroll
      for (int t = 0; t < 4; t++) acc[t] = MFMA16(hf, sb[(c - 3) & 1][t], acc[t]);
      if (c + 2 <= 15) {
#pragma unroll
        for (int t = 0; t < 4; t++)
          sb[(c - 3) & 1][t] =
              *(const bf16x8*)&W2f[(((c + 2) * 32 + wave * 4 + t) * 64 + lane) * 8];
      }
    }
#pragma unroll
    for (int t = 0; t < 4; t++) {
      int col = wave * 64 + t * 16 + colq;
      int cc = col >> 5, gh = (col & 31) >> 3, sl = col & 7;
#pragma unroll
      for (int r = 0; r < 4; r++)
        h2F[cc][gq * 4 + r + gh * 16][sl] = f2bf(fast_tanh(acc[t][r]));
    }
    __syncthreads();
    // ---- L3: dL = h2 @ W3 + b3 (each wave owns 16 of the 128 cols;
    //      C-fragment layout == state ownership, so result stays in regs) ----
    f32x4 a3 = splat4(b3v);
#pragma unroll
    for (int c = 0; c < 16; c++) {
      bf16x8 hf = *(const bf16x8*)&h2F[c][lane][0];
      a3 = MFMA16(hf, w3f[c], a3);
    }
    return a3;
  };

#pragma unroll 1
  for (int s = 0; s < CSTEPS; s++) {
    const float t0s = times[s], t1s = times[s + 1];
    const float dt = t1s - t0s;

    f32x4 k1 = eval(v, t0s);
    f32x4 st;
#pragma unroll
    for (int r = 0; r < 4; r++) st[r] = v[r] + 0.5f * dt * k1[r];
    f32x4 k2 = eval(st, t0s + 0.5f * dt);
#pragma unroll
    for (int r = 0; r < 4; r++) st[r] = v[r] + 0.5f * dt * k2[r];
    f32x4 k3 = eval(st, t0s + 0.5f * dt);
#pragma unroll
    for (int r = 0; r < 4; r++) st[r] = v[r] + dt * k3[r];
    f32x4 k4 = eval(st, t1s);

#pragma unroll
    for (int r = 0; r < 4; r++)
      v[r] += dt * (1.0f / 6.0f) * (k1[r] + 2.0f * k2[r] + 2.0f * k3[r] + k4[r]);

#pragma unroll
    for (int r = 0; r < 4; r++)
      vhist[((s + 1) * CB + r0 + gq * 4 + r) * CLD + d_] = v[r];
  }
}

// ---------------------------------------------------------------------------
// Kernel 4: fused decoder (unchanged from round 1 — verified). 1600 blocks x
// 512 threads, 64 rows/block; latent gather fused into A-tile build.
// ---------------------------------------------------------------------------
__global__ __launch_bounds__(512) void dec_kernel(
    const float* __restrict__ x, const u16* __restrict__ zbf,
    const float* __restrict__ vhist, const int* __restrict__ rank,
    const u16* __restrict__ Wt1, const u16* __restrict__ Wt2, const u16* __restrict__ Wt3,
    const float* __restrict__ b1, const float* __restrict__ b2, const float* __restrict__ b3,
    float* __restrict__ out) {
  __shared__ __align__(16) u16 hA[4][16][64][8];   // A (chunks 0..8), then h2
  __shared__ __align__(16) u16 h1F[4][16][64][8];  // h1
  __shared__ int rk[104];

  const int tid = threadIdx.x, lane = tid & 63, wave = tid >> 6;
  const int R0 = blockIdx.x * 64;

  if (tid < CK) rk[tid] = rank[tid];
  __syncthreads();

  {  // build A-tile (fused latent gather)
    const int i = tid >> 3, j = tid & 7;
    const int row = R0 + i;
    const int b = row / CN;
    const float xv = x[row];
    int gi = (int)(xv * 100.0f + 0.5f);
    gi = gi < 0 ? 0 : (gi > 100 ? 100 : gi);
    const int k = rk[gi];
    const int mt = i >> 4, m = i & 15;
    const float4* lp = (const float4*)&vhist[((k * CB) + b) * CLD + j * 16];
    float4 l0 = lp[0], l1 = lp[1], l2 = lp[2], l3 = lp[3];
    u16x8 lv0, lv1;
    lv0[0] = f2bf(l0.x); lv0[1] = f2bf(l0.y); lv0[2] = f2bf(l0.z); lv0[3] = f2bf(l0.w);
    lv0[4] = f2bf(l1.x); lv0[5] = f2bf(l1.y); lv0[6] = f2bf(l1.z); lv0[7] = f2bf(l1.w);
    lv1[0] = f2bf(l2.x); lv1[1] = f2bf(l2.y); lv1[2] = f2bf(l2.z); lv1[3] = f2bf(l2.w);
    lv1[4] = f2bf(l3.x); lv1[5] = f2bf(l3.y); lv1[6] = f2bf(l3.z); lv1[7] = f2bf(l3.w);
    const int c = j >> 1, gh = (j & 1) * 2;
    *(u16x8*)&hA[mt][c][m + gh * 16][0] = lv0;
    *(u16x8*)&hA[mt][c][m + (gh + 1) * 16][0] = lv1;
    const u16x8* zp = (const u16x8*)&zbf[b * CLD + j * 16];
    u16x8 zv0 = zp[0], zv1 = zp[1];
    *(u16x8*)&hA[mt][4 + c][m + gh * 16][0] = zv0;
    *(u16x8*)&hA[mt][4 + c][m + (gh + 1) * 16][0] = zv1;
    if (j == 0) {
      hA[mt][8][m][0] = f2bf(xv);
#pragma unroll
      for (int q = 1; q < 8; q++) hA[mt][8][m][q] = 0;
    } else if (j < 4) {
      u16x8 zz = {0, 0, 0, 0, 0, 0, 0, 0};
      *(u16x8*)&hA[mt][8][m + j * 16][0] = zz;
    }
  }
  __syncthreads();

  const int colq = lane & 15, gq = lane >> 4;
  const int nb = wave * 64;
  f32x4 acc[4][4];

  // ---- L1 ----
#pragma unroll
  for (int nt = 0; nt < 4; nt++) {
    float bv = b1[nb + nt * 16 + colq];
#pragma unroll
    for (int mt = 0; mt < 4; mt++) acc[mt][nt] = splat4(bv);
  }
#pragma unroll
  for (int c = 0; c < 9; c++) {
    bf16x8 af0 = *(const bf16x8*)&hA[0][c][lane][0];
    bf16x8 af1 = *(const bf16x8*)&hA[1][c][lane][0];
    bf16x8 af2 = *(const bf16x8*)&hA[2][c][lane][0];
    bf16x8 af3 = *(const bf16x8*)&hA[3][c][lane][0];
#pragma unroll
    for (int nt = 0; nt < 4; nt++) {
      bf16x8 bfv = *(const bf16x8*)&Wt1[(size_t)(nb + nt * 16 + colq) * 288 + c * 32 + gq * 8];
      acc[0][nt] = MFMA16(af0, bfv, acc[0][nt]);
      acc[1][nt] = MFMA16(af1, bfv, acc[1][nt]);
      acc[2][nt] = MFMA16(af2, bfv, acc[2][nt]);
      acc[3][nt] = MFMA16(af3, bfv, acc[3][nt]);
    }
  }
#pragma unroll
  for (int mt = 0; mt < 4; mt++)
#pragma unroll
    for (int nt = 0; nt < 4; nt++) {
      int col = nb + nt * 16 + colq;
      int cc = col >> 5, gh = (col & 31) >> 3, sl = col & 7;
#pragma unroll
      for (int r = 0; r < 4; r++)
        h1F[mt][cc][gq * 4 + r + gh * 16][sl] = f2bf(fmaxf(acc[mt][nt][r], 0.0f));
    }
  __syncthreads();

  // ---- L2 ----
#pragma unroll
  for (int nt = 0; nt < 4; nt++) {
    float bv = b2[nb + nt * 16 + colq];
#pragma unroll
    for (int mt = 0; mt < 4; mt++) acc[mt][nt] = splat4(bv);
  }
#pragma unroll
  for (int c = 0; c < 16; c++) {
    bf16x8 af0 = *(const bf16x8*)&h1F[0][c][lane][0];
    bf16x8 af1 = *(const bf16x8*)&h1F[1][c][lane][0];
    bf16x8 af2 = *(const bf16x8*)&h1F[2][c][lane][0];
    bf16x8 af3 = *(const bf16x8*)&h1F[3][c][lane][0];
#pragma unroll
    for (int nt = 0; nt < 4; nt++) {
      bf16x8 bfv = *(const bf16x8*)&Wt2[(size_t)(nb + nt * 16 + colq) * 512 + c * 32 + gq * 8];
      acc[0][nt] = MFMA16(af0, bfv, acc[0][nt]);
      acc[1][nt] = MFMA16(af1, bfv, acc[1][nt]);
      acc[2][nt] = MFMA16(af2, bfv, acc[2][nt]);
      acc[3][nt] = MFMA16(af3, bfv, acc[3][nt]);
    }
  }
#pragma unroll
  for (int mt = 0; mt < 4; mt++)
#pragma unroll
    for (int nt = 0; nt < 4; nt++) {
      int col = nb + nt * 16 + colq;
      int cc = col >> 5, gh = (col & 31) >> 3, sl = col & 7;
#pragma unroll
      for (int r = 0; r < 4; r++)
        hA[mt][cc][gq * 4 + r + gh * 16][sl] = f2bf(fmaxf(acc[mt][nt][r], 0.0f));
    }
  __syncthreads();

  // ---- L3 ----
#pragma unroll
  for (int nt = 0; nt < 4; nt++) {
    float bv = b3[nb + nt * 16 + colq];
#pragma unroll
    for (int mt = 0; mt < 4; mt++) acc[mt][nt] = splat4(bv);
  }
#pragma unroll
  for (int c = 0; c < 16; c++) {
    bf16x8 af0 = *(const bf16x8*)&hA[0][c][lane][0];
    bf16x8 af1 = *(const bf16x8*)&hA[1][c][lane][0];
    bf16x8 af2 = *(const bf16x8*)&hA[2][c][lane][0];
    bf16x8 af3 = *(const bf16x8*)&hA[3][c][lane][0];
#pragma unroll
    for (int nt = 0; nt < 4; nt++) {
      bf16x8 bfv = *(const bf16x8*)&Wt3[(size_t)(nb + nt * 16 + colq) * 512 + c * 32 + gq * 8];
      acc[0][nt] = MFMA16(af0, bfv, acc[0][nt]);
      acc[1][nt] = MFMA16(af1, bfv, acc[1][nt]);
      acc[2][nt] = MFMA16(af2, bfv, acc[2][nt]);
      acc[3][nt] = MFMA16(af3, bfv, acc[3][nt]);
    }
  }
#pragma unroll
  for (int mt = 0; mt < 4; mt++)
#pragma unroll
    for (int nt = 0; nt < 4; nt++) {
      int col = nb + nt * 16 + colq;
#pragma unroll
      for (int r = 0; r < 4; r++) {
        int row = R0 + mt * 16 + gq * 4 + r;
        out[(size_t)row * CHD + col] = fmaxf(acc[mt][nt][r], 0.0f);
      }
    }
}

// ---------------------------------------------------------------------------
extern "C" void kernel_launch(void* const* d_in, const int* in_sizes, int n_in,
                              void* d_out, int out_size, void* d_ws, size_t ws_size,
                              hipStream_t stream) {
  (void)in_sizes; (void)n_in; (void)out_size; (void)ws_size;

  const float* x   = (const float*)d_in[0];
  const float* z   = (const float*)d_in[1];
  const float* t0  = (const float*)d_in[2];
  const float* oW1 = (const float*)d_in[3];
  const float* ob1 = (const float*)d_in[4];
  const float* oW2 = (const float*)d_in[5];
  const float* ob2 = (const float*)d_in[6];
  const float* oW3 = (const float*)d_in[7];
  const float* ob3 = (const float*)d_in[8];
  const float* dW1 = (const float*)d_in[9];
  const float* db1 = (const float*)d_in[10];
  const float* dW2 = (const float*)d_in[11];
  const float* db2 = (const float*)d_in[12];
  const float* dW3 = (const float*)d_in[13];
  const float* db3 = (const float*)d_in[14];

  char* ws = (char*)d_ws;
  size_t off = 0;
  auto alloc = [&](size_t bytes) {
    void* p = ws + off;
    off = (off + bytes + 255) & ~(size_t)255;
    return p;
  };
  float* vhist = (float*)alloc((size_t)CK * CB * CLD * 4);  // 26.5 MB
  u16* W1f  = (u16*)alloc(65536 * 2);
  u16* W1hf = (u16*)alloc(65536 * 2);
  u16* W2f  = (u16*)alloc(262144 * 2);
  u16* W3f  = (u16*)alloc(65536 * 2);
  u16* dWt1 = (u16*)alloc(512 * 288 * 2);
  u16* dWt2 = (u16*)alloc(512 * 512 * 2);
  u16* dWt3 = (u16*)alloc(512 * 512 * 2);
  u16* zbf  = (u16*)alloc(512 * 128 * 2);
  float* times = (float*)alloc(512);
  int* rank    = (int*)alloc(512);

  build_times_kernel<<<dim3(1), dim3(256), 0, stream>>>(x, t0, times, rank);
  prep_kernel<<<dim3(512), dim3(256), 0, stream>>>(oW1, oW2, oW3, dW1, dW2, dW3, z,
                                                   W1f, W1hf, W2f, W3f,
                                                   dWt1, dWt2, dWt3, zbf);
  ode_kernel<<<dim3(32), dim3(512), 0, stream>>>(z, W1f, W1hf, W2f, W3f, oW1,
                                                 ob1, ob2, ob3, times, vhist);
  dec_kernel<<<dim3(1600), dim3(512), 0, stream>>>(x, zbf, vhist, rank,
                                                   dWt1, dWt2, dWt3, db1, db2, db3,
                                                   (float*)d_out);
}

// Round 3
// 5689.748 us; speedup vs baseline: 2.2865x; 1.0694x over previous
//
#include <hip/hip_runtime.h>

// AbstractODEDecoder: unique-time grid + RK4 latent ODE + fused MLP decoder.
// B=512, N=200, ZD=256, LD=128, HD=512, T=100, K=101.

typedef unsigned short u16;
typedef float f32x4 __attribute__((ext_vector_type(4)));
typedef short bf16x8 __attribute__((ext_vector_type(8)));
typedef u16 u16x8 __attribute__((ext_vector_type(8)));

#define MFMA16(a, b, c) __builtin_amdgcn_mfma_f32_16x16x32_bf16((a), (b), (c), 0, 0, 0)

constexpr int CB = 512;
constexpr int CN = 200;
constexpr int CZD = 256;
constexpr int CLD = 128;
constexpr int CHD = 512;
constexpr int CK = 101;
constexpr int CSTEPS = 100;

__device__ __forceinline__ u16 f2bf(float f) {
  unsigned u = __builtin_bit_cast(unsigned, f);
  u = (u + 0x7FFFu + ((u >> 16) & 1u)) >> 16;  // round-to-nearest-even bf16
  return (u16)u;
}

__device__ __forceinline__ f32x4 splat4(float v) {
  f32x4 r; r[0] = v; r[1] = v; r[2] = v; r[3] = v; return r;
}

__device__ __forceinline__ float fast_tanh(float x) {
  float e = __expf(2.0f * x);
  return 1.0f - 2.0f / (e + 1.0f);
}

// ---------------------------------------------------------------------------
// Kernel 1: unique-time grid (presence bitmap -> sorted times + rank)
// ---------------------------------------------------------------------------
__global__ void build_times_kernel(const float* __restrict__ x, const float* __restrict__ t0p,
                                   float* __restrict__ times, int* __restrict__ rank) {
  __shared__ int pres[128];
  const int tid = threadIdx.x;
  if (tid < 128) pres[tid] = 0;
  __syncthreads();
  for (int i = tid; i < CB * CN; i += blockDim.x) {
    float v = x[i];
    int gi = (int)(v * 100.0f + 0.5f);
    gi = gi < 0 ? 0 : (gi > 100 ? 100 : gi);
    pres[gi] = 1;
  }
  if (tid == 0) {
    float t0 = t0p[0];
    int gi = (int)(t0 * 100.0f + 0.5f);
    gi = gi < 0 ? 0 : (gi > 100 ? 100 : gi);
    pres[gi] = 1;
  }
  __syncthreads();
  if (tid == 0) {
    int c = 0;
    for (int i = 0; i <= 100; i++) {
      if (pres[i]) { times[c] = (float)i / 100.0f; rank[i] = c; c++; }
      else rank[i] = -1;
    }
    for (int j = c; j < CK; j++) times[j] = 1.0f;  // fill_value=1.0
  }
}

// ---------------------------------------------------------------------------
// Kernel 2: weight prep.
// ODE weights in fragment-linear bf16 layout: element ((c*NT + tile)*64 + lane)*8 + j
//   holds W[k = c*32 + (lane>>4)*8 + j][n = tile*16 + (lane&15)].
//   W1f: ode_W1 rows 0..127 (evolving latent). W1hf: rows 128..255 (z_hi, for c_pre).
//   W2f: 16 chunks x 32 tiles. W3f: 16 chunks x 8 tiles (128 cols).
// Decoder weights keep the round-1 [n][k] layout (dWt1 K-order: latent|z_hi|x).
// ---------------------------------------------------------------------------
__global__ void prep_kernel(
    const float* __restrict__ oW1, const float* __restrict__ oW2, const float* __restrict__ oW3,
    const float* __restrict__ dW1, const float* __restrict__ dW2, const float* __restrict__ dW3,
    const float* __restrict__ z,
    u16* __restrict__ W1f, u16* __restrict__ W1hf, u16* __restrict__ W2f, u16* __restrict__ W3f,
    u16* __restrict__ dWt1, u16* __restrict__ dWt2, u16* __restrict__ dWt3,
    u16* __restrict__ zbf) {
  const int tid = blockIdx.x * blockDim.x + threadIdx.x;
  const int nth = gridDim.x * blockDim.x;
  // W1f / W1hf: 4 chunks x 32 tiles
  for (int i = tid; i < 65536; i += nth) {
    int j = i & 7, lane = (i >> 3) & 63, tc = i >> 9, tile = tc & 31, c = tc >> 5;
    int k = c * 32 + (lane >> 4) * 8 + j, n = tile * 16 + (lane & 15);
    W1f[i]  = f2bf(oW1[k * 512 + n]);
    W1hf[i] = f2bf(oW1[(128 + k) * 512 + n]);
  }
  // W2f: 16 chunks x 32 tiles
  for (int i = tid; i < 262144; i += nth) {
    int j = i & 7, lane = (i >> 3) & 63, tc = i >> 9, tile = tc & 31, c = tc >> 5;
    int k = c * 32 + (lane >> 4) * 8 + j, n = tile * 16 + (lane & 15);
    W2f[i] = f2bf(oW2[k * 512 + n]);
  }
  // W3f: 16 chunks x 8 tiles
  for (int i = tid; i < 65536; i += nth) {
    int j = i & 7, lane = (i >> 3) & 63, tc = i >> 9, tile = tc & 7, c = tc >> 3;
    int k = c * 32 + (lane >> 4) * 8 + j, n = tile * 16 + (lane & 15);
    W3f[i] = f2bf(oW3[k * 128 + n]);
  }
  // decoder weights (round-1 layouts, verified)
  for (int i = tid; i < 512 * 288; i += nth) {
    int n = i / 288, k = i - n * 288;
    dWt1[i] = (k < 256) ? f2bf(dW1[(k + 1) * 512 + n])
                        : (k == 256 ? f2bf(dW1[n]) : (u16)0);
  }
  for (int i = tid; i < 512 * 512; i += nth) {
    int n = i >> 9, k = i & 511;
    dWt2[i] = f2bf(dW2[k * 512 + n]);
  }
  for (int i = tid; i < 512 * 512; i += nth) {
    int n = i >> 9, k = i & 511;
    dWt3[i] = f2bf(dW3[k * 512 + n]);
  }
  for (int i = tid; i < 512 * 128; i += nth) {
    int b = i >> 7, d = i & 127;
    zbf[i] = f2bf(z[b * 256 + 128 + d]);
  }
}

// ---------------------------------------------------------------------------
// Kernel 3: RK4 ODE integrate. 32 blocks x 512 threads (8 waves), 16 rows/block.
// VGPR budget discipline (round-2 spilled at 128 VGPRs): only W3 resident in
// VGPRs (64 regs) + 4-deep W2 stream ring (64 regs). W1 lives in LDS; h1/h2
// time-share one LDS fragment buffer. z_hi folded into c_pre acc-init; t is an
// f32 rank-1 update. State in the L3 C-fragment layout -> RK math is pure regs.
// ---------------------------------------------------------------------------
__global__ __launch_bounds__(512, 2) void ode_kernel(
    const float* __restrict__ z,
    const u16* __restrict__ W1f, const u16* __restrict__ W1hf,
    const u16* __restrict__ W2f, const u16* __restrict__ W3f,
    const float* __restrict__ oW1,
    const float* __restrict__ b1, const float* __restrict__ b2, const float* __restrict__ b3,
    const float* __restrict__ times, float* __restrict__ vhist) {
  __shared__ __align__(16) u16 W1L[4 * 32 * 64 * 8];  // 128 KiB, layout == W1f
  __shared__ __align__(16) u16 aF[4][64][8];          // A fragments (K=128), 4 KiB
  __shared__ __align__(16) u16 hF[16][64][8];         // h1/h2 time-shared, 16 KiB
  __shared__ float ts[104];

  const int tid = threadIdx.x, lane = tid & 63, wave = tid >> 6;
  const int colq = lane & 15, gq = lane >> 4;
  const int r0 = blockIdx.x * 16;
  const int d_ = wave * 16 + colq;  // state column this thread owns

  // stage W1 into LDS
  for (int i = tid; i < 8192; i += 512)
    *(u16x8*)&W1L[i * 8] = *(const u16x8*)&W1f[i * 8];
  if (tid < CK) ts[tid] = times[tid];

  // resident W3 fragments (64 VGPRs)
  bf16x8 w3f[16];
#pragma unroll
  for (int c = 0; c < 16; c++)
    w3f[c] = *(const bf16x8*)&W3f[((c * 8 + wave) * 64 + lane) * 8];

  float b2v[4], wtv[4];
#pragma unroll
  for (int t = 0; t < 4; t++) {
    int col = wave * 64 + t * 16 + colq;
    b2v[t] = b2[col];
    wtv[t] = oW1[256 * 512 + col];  // t-row of ode_W1
  }
  const float b3v = b3[d_];

  // state + vhist[0]
  f32x4 v;
#pragma unroll
  for (int r = 0; r < 4; r++) {
    v[r] = z[(r0 + gq * 4 + r) * CZD + d_];
    vhist[(0 * CB + r0 + gq * 4 + r) * CLD + d_] = v[r];
  }

  // --- c_pre = b1 + z_hi @ W1[128:256]  (constant across all evals) ---
  {
    int c = d_ >> 5, gh = (d_ & 31) >> 3, sl = d_ & 7;
#pragma unroll
    for (int r = 0; r < 4; r++)
      aF[c][gq * 4 + r + gh * 16][sl] = f2bf(z[(r0 + gq * 4 + r) * CZD + 128 + d_]);
  }
  __syncthreads();
  f32x4 cpre[4];
#pragma unroll
  for (int t = 0; t < 4; t++) cpre[t] = splat4(b1[wave * 64 + t * 16 + colq]);
#pragma unroll
  for (int c = 0; c < 4; c++) {
    bf16x8 af = *(const bf16x8*)&aF[c][lane][0];
#pragma unroll
    for (int t = 0; t < 4; t++)
      cpre[t] = MFMA16(af, *(const bf16x8*)&W1hf[((c * 32 + wave * 4 + t) * 64 + lane) * 8],
                       cpre[t]);
  }
  __syncthreads();  // aF reads done before first eval overwrites it

  auto eval = [&](f32x4 si, float tstage) -> f32x4 {
    // W2 stream ring: 4-deep, statically indexed (full unroll). Prologue:
    // issue chunks 0..3 now; they land under the A-barrier + L1 phase.
    bf16x8 sb[4][4];
#pragma unroll
    for (int c0 = 0; c0 < 4; c0++)
#pragma unroll
      for (int t = 0; t < 4; t++)
        sb[c0][t] = *(const bf16x8*)&W2f[((c0 * 32 + wave * 4 + t) * 64 + lane) * 8];

    // write evolving-latent A fragments
    {
      int c = d_ >> 5, gh = (d_ & 31) >> 3, sl = d_ & 7;
#pragma unroll
      for (int r = 0; r < 4; r++)
        aF[c][gq * 4 + r + gh * 16][sl] = f2bf(si[r]);
    }
    __syncthreads();  // bar1: A ready (also fences prev-eval hF/aF readers)

    // ---- L1: h1 = tanh(cpre + t*wt + vL @ W1)  (W1 from LDS) ----
    f32x4 acc[4];
#pragma unroll
    for (int t = 0; t < 4; t++) {
      f32x4 a;
#pragma unroll
      for (int r = 0; r < 4; r++) a[r] = cpre[t][r] + tstage * wtv[t];
      acc[t] = a;
    }
#pragma unroll
    for (int c = 0; c < 4; c++) {
      bf16x8 af = *(const bf16x8*)&aF[c][lane][0];
#pragma unroll
      for (int t = 0; t < 4; t++)
        acc[t] = MFMA16(af, *(const bf16x8*)&W1L[((c * 32 + wave * 4 + t) * 64 + lane) * 8],
                        acc[t]);
    }
#pragma unroll
    for (int t = 0; t < 4; t++) {
      int col = wave * 64 + t * 16 + colq;
      int cc = col >> 5, gh = (col & 31) >> 3, sl = col & 7;
#pragma unroll
      for (int r = 0; r < 4; r++)
        hF[cc][gq * 4 + r + gh * 16][sl] = f2bf(fast_tanh(acc[t][r]));
    }
    __syncthreads();  // bar2: h1 ready

    // ---- L2: h2 = tanh(h1 @ W2 + b2); all 16 chunks streamed, 4-deep ring ----
#pragma unroll
    for (int t = 0; t < 4; t++) acc[t] = splat4(b2v[t]);
#pragma unroll
    for (int c = 0; c < 16; c++) {
      bf16x8 hf = *(const bf16x8*)&hF[c][lane][0];
#pragma unroll
      for (int t = 0; t < 4; t++) acc[t] = MFMA16(hf, sb[c & 3][t], acc[t]);
      if (c + 4 < 16) {
#pragma unroll
        for (int t = 0; t < 4; t++)
          sb[c & 3][t] =
              *(const bf16x8*)&W2f[(((c + 4) * 32 + wave * 4 + t) * 64 + lane) * 8];
      }
    }
    __syncthreads();  // bar3: all h1 reads done, safe to overwrite hF
#pragma unroll
    for (int t = 0; t < 4; t++) {
      int col = wave * 64 + t * 16 + colq;
      int cc = col >> 5, gh = (col & 31) >> 3, sl = col & 7;
#pragma unroll
      for (int r = 0; r < 4; r++)
        hF[cc][gq * 4 + r + gh * 16][sl] = f2bf(fast_tanh(acc[t][r]));
    }
    __syncthreads();  // bar4: h2 ready

    // ---- L3: dL = h2 @ W3 + b3 (resident W3; result stays in this thread's
    //      registers because C-fragment layout == state ownership) ----
    f32x4 a3 = splat4(b3v);
#pragma unroll
    for (int c = 0; c < 16; c++) {
      bf16x8 hf = *(const bf16x8*)&hF[c][lane][0];
      a3 = MFMA16(hf, w3f[c], a3);
    }
    return a3;
  };

#pragma unroll 1
  for (int s = 0; s < CSTEPS; s++) {
    const float t0s = ts[s], t1s = ts[s + 1];
    const float dt = t1s - t0s;

    f32x4 k1 = eval(v, t0s);
    f32x4 st;
#pragma unroll
    for (int r = 0; r < 4; r++) st[r] = v[r] + 0.5f * dt * k1[r];
    f32x4 k2 = eval(st, t0s + 0.5f * dt);
#pragma unroll
    for (int r = 0; r < 4; r++) st[r] = v[r] + 0.5f * dt * k2[r];
    f32x4 k3 = eval(st, t0s + 0.5f * dt);
#pragma unroll
    for (int r = 0; r < 4; r++) st[r] = v[r] + dt * k3[r];
    f32x4 k4 = eval(st, t1s);

#pragma unroll
    for (int r = 0; r < 4; r++)
      v[r] += dt * (1.0f / 6.0f) * (k1[r] + 2.0f * k2[r] + 2.0f * k3[r] + k4[r]);

#pragma unroll
    for (int r = 0; r < 4; r++)
      vhist[((s + 1) * CB + r0 + gq * 4 + r) * CLD + d_] = v[r];
  }
}

// ---------------------------------------------------------------------------
// Kernel 4: fused decoder (unchanged — verified). 1600 blocks x 512 threads,
// 64 rows/block; latent gather fused into A-tile build.
// ---------------------------------------------------------------------------
__global__ __launch_bounds__(512) void dec_kernel(
    const float* __restrict__ x, const u16* __restrict__ zbf,
    const float* __restrict__ vhist, const int* __restrict__ rank,
    const u16* __restrict__ Wt1, const u16* __restrict__ Wt2, const u16* __restrict__ Wt3,
    const float* __restrict__ b1, const float* __restrict__ b2, const float* __restrict__ b3,
    float* __restrict__ out) {
  __shared__ __align__(16) u16 hA[4][16][64][8];   // A (chunks 0..8), then h2
  __shared__ __align__(16) u16 h1F[4][16][64][8];  // h1
  __shared__ int rk[104];

  const int tid = threadIdx.x, lane = tid & 63, wave = tid >> 6;
  const int R0 = blockIdx.x * 64;

  if (tid < CK) rk[tid] = rank[tid];
  __syncthreads();

  {  // build A-tile (fused latent gather)
    const int i = tid >> 3, j = tid & 7;
    const int row = R0 + i;
    const int b = row / CN;
    const float xv = x[row];
    int gi = (int)(xv * 100.0f + 0.5f);
    gi = gi < 0 ? 0 : (gi > 100 ? 100 : gi);
    const int k = rk[gi];
    const int mt = i >> 4, m = i & 15;
    const float4* lp = (const float4*)&vhist[((k * CB) + b) * CLD + j * 16];
    float4 l0 = lp[0], l1 = lp[1], l2 = lp[2], l3 = lp[3];
    u16x8 lv0, lv1;
    lv0[0] = f2bf(l0.x); lv0[1] = f2bf(l0.y); lv0[2] = f2bf(l0.z); lv0[3] = f2bf(l0.w);
    lv0[4] = f2bf(l1.x); lv0[5] = f2bf(l1.y); lv0[6] = f2bf(l1.z); lv0[7] = f2bf(l1.w);
    lv1[0] = f2bf(l2.x); lv1[1] = f2bf(l2.y); lv1[2] = f2bf(l2.z); lv1[3] = f2bf(l2.w);
    lv1[4] = f2bf(l3.x); lv1[5] = f2bf(l3.y); lv1[6] = f2bf(l3.z); lv1[7] = f2bf(l3.w);
    const int c = j >> 1, gh = (j & 1) * 2;
    *(u16x8*)&hA[mt][c][m + gh * 16][0] = lv0;
    *(u16x8*)&hA[mt][c][m + (gh + 1) * 16][0] = lv1;
    const u16x8* zp = (const u16x8*)&zbf[b * CLD + j * 16];
    u16x8 zv0 = zp[0], zv1 = zp[1];
    *(u16x8*)&hA[mt][4 + c][m + gh * 16][0] = zv0;
    *(u16x8*)&hA[mt][4 + c][m + (gh + 1) * 16][0] = zv1;
    if (j == 0) {
      hA[mt][8][m][0] = f2bf(xv);
#pragma unroll
      for (int q = 1; q < 8; q++) hA[mt][8][m][q] = 0;
    } else if (j < 4) {
      u16x8 zz = {0, 0, 0, 0, 0, 0, 0, 0};
      *(u16x8*)&hA[mt][8][m + j * 16][0] = zz;
    }
  }
  __syncthreads();

  const int colq = lane & 15, gq = lane >> 4;
  const int nb = wave * 64;
  f32x4 acc[4][4];

  // ---- L1 ----
#pragma unroll
  for (int nt = 0; nt < 4; nt++) {
    float bv = b1[nb + nt * 16 + colq];
#pragma unroll
    for (int mt = 0; mt < 4; mt++) acc[mt][nt] = splat4(bv);
  }
#pragma unroll
  for (int c = 0; c < 9; c++) {
    bf16x8 af0 = *(const bf16x8*)&hA[0][c][lane][0];
    bf16x8 af1 = *(const bf16x8*)&hA[1][c][lane][0];
    bf16x8 af2 = *(const bf16x8*)&hA[2][c][lane][0];
    bf16x8 af3 = *(const bf16x8*)&hA[3][c][lane][0];
#pragma unroll
    for (int nt = 0; nt < 4; nt++) {
      bf16x8 bfv = *(const bf16x8*)&Wt1[(size_t)(nb + nt * 16 + colq) * 288 + c * 32 + gq * 8];
      acc[0][nt] = MFMA16(af0, bfv, acc[0][nt]);
      acc[1][nt] = MFMA16(af1, bfv, acc[1][nt]);
      acc[2][nt] = MFMA16(af2, bfv, acc[2][nt]);
      acc[3][nt] = MFMA16(af3, bfv, acc[3][nt]);
    }
  }
#pragma unroll
  for (int mt = 0; mt < 4; mt++)
#pragma unroll
    for (int nt = 0; nt < 4; nt++) {
      int col = nb + nt * 16 + colq;
      int cc = col >> 5, gh = (col & 31) >> 3, sl = col & 7;
#pragma unroll
      for (int r = 0; r < 4; r++)
        h1F[mt][cc][gq * 4 + r + gh * 16][sl] = f2bf(fmaxf(acc[mt][nt][r], 0.0f));
    }
  __syncthreads();

  // ---- L2 ----
#pragma unroll
  for (int nt = 0; nt < 4; nt++) {
    float bv = b2[nb + nt * 16 + colq];
#pragma unroll
    for (int mt = 0; mt < 4; mt++) acc[mt][nt] = splat4(bv);
  }
#pragma unroll
  for (int c = 0; c < 16; c++) {
    bf16x8 af0 = *(const bf16x8*)&h1F[0][c][lane][0];
    bf16x8 af1 = *(const bf16x8*)&h1F[1][c][lane][0];
    bf16x8 af2 = *(const bf16x8*)&h1F[2][c][lane][0];
    bf16x8 af3 = *(const bf16x8*)&h1F[3][c][lane][0];
#pragma unroll
    for (int nt = 0; nt < 4; nt++) {
      bf16x8 bfv = *(const bf16x8*)&Wt2[(size_t)(nb + nt * 16 + colq) * 512 + c * 32 + gq * 8];
      acc[0][nt] = MFMA16(af0, bfv, acc[0][nt]);
      acc[1][nt] = MFMA16(af1, bfv, acc[1][nt]);
      acc[2][nt] = MFMA16(af2, bfv, acc[2][nt]);
      acc[3][nt] = MFMA16(af3, bfv, acc[3][nt]);
    }
  }
#pragma unroll
  for (int mt = 0; mt < 4; mt++)
#pragma unroll
    for (int nt = 0; nt < 4; nt++) {
      int col = nb + nt * 16 + colq;
      int cc = col >> 5, gh = (col & 31) >> 3, sl = col & 7;
#pragma unroll
      for (int r = 0; r < 4; r++)
        hA[mt][cc][gq * 4 + r + gh * 16][sl] = f2bf(fmaxf(acc[mt][nt][r], 0.0f));
    }
  __syncthreads();

  // ---- L3 ----
#pragma unroll
  for (int nt = 0; nt < 4; nt++) {
    float bv = b3[nb + nt * 16 + colq];
#pragma unroll
    for (int mt = 0; mt < 4; mt++) acc[mt][nt] = splat4(bv);
  }
#pragma unroll
  for (int c = 0; c < 16; c++) {
    bf16x8 af0 = *(const bf16x8*)&hA[0][c][lane][0];
    bf16x8 af1 = *(const bf16x8*)&hA[1][c][lane][0];
    bf16x8 af2 = *(const bf16x8*)&hA[2][c][lane][0];
    bf16x8 af3 = *(const bf16x8*)&hA[3][c][lane][0];
#pragma unroll
    for (int nt = 0; nt < 4; nt++) {
      bf16x8 bfv = *(const bf16x8*)&Wt3[(size_t)(nb + nt * 16 + colq) * 512 + c * 32 + gq * 8];
      acc[0][nt] = MFMA16(af0, bfv, acc[0][nt]);
      acc[1][nt] = MFMA16(af1, bfv, acc[1][nt]);
      acc[2][nt] = MFMA16(af2, bfv, acc[2][nt]);
      acc[3][nt] = MFMA16(af3, bfv, acc[3][nt]);
    }
  }
#pragma unroll
  for (int mt = 0; mt < 4; mt++)
#pragma unroll
    for (int nt = 0; nt < 4; nt++) {
      int col = nb + nt * 16 + colq;
#pragma unroll
      for (int r = 0; r < 4; r++) {
        int row = R0 + mt * 16 + gq * 4 + r;
        out[(size_t)row * CHD + col] = fmaxf(acc[mt][nt][r], 0.0f);
      }
    }
}

// ---------------------------------------------------------------------------
extern "C" void kernel_launch(void* const* d_in, const int* in_sizes, int n_in,
                              void* d_out, int out_size, void* d_ws, size_t ws_size,
                              hipStream_t stream) {
  (void)in_sizes; (void)n_in; (void)out_size; (void)ws_size;

  const float* x   = (const float*)d_in[0];
  const float* z   = (const float*)d_in[1];
  const float* t0  = (const float*)d_in[2];
  const float* oW1 = (const float*)d_in[3];
  const float* ob1 = (const float*)d_in[4];
  const float* oW2 = (const float*)d_in[5];
  const float* ob2 = (const float*)d_in[6];
  const float* oW3 = (const float*)d_in[7];
  const float* ob3 = (const float*)d_in[8];
  const float* dW1 = (const float*)d_in[9];
  const float* db1 = (const float*)d_in[10];
  const float* dW2 = (const float*)d_in[11];
  const float* db2 = (const float*)d_in[12];
  const float* dW3 = (const float*)d_in[13];
  const float* db3 = (const float*)d_in[14];

  char* ws = (char*)d_ws;
  size_t off = 0;
  auto alloc = [&](size_t bytes) {
    void* p = ws + off;
    off = (off + bytes + 255) & ~(size_t)255;
    return p;
  };
  float* vhist = (float*)alloc((size_t)CK * CB * CLD * 4);  // 26.5 MB
  u16* W1f  = (u16*)alloc(65536 * 2);
  u16* W1hf = (u16*)alloc(65536 * 2);
  u16* W2f  = (u16*)alloc(262144 * 2);
  u16* W3f  = (u16*)alloc(65536 * 2);
  u16* dWt1 = (u16*)alloc(512 * 288 * 2);
  u16* dWt2 = (u16*)alloc(512 * 512 * 2);
  u16* dWt3 = (u16*)alloc(512 * 512 * 2);
  u16* zbf  = (u16*)alloc(512 * 128 * 2);
  float* times = (float*)alloc(512);
  int* rank    = (int*)alloc(512);

  build_times_kernel<<<dim3(1), dim3(256), 0, stream>>>(x, t0, times, rank);
  prep_kernel<<<dim3(512), dim3(256), 0, stream>>>(oW1, oW2, oW3, dW1, dW2, dW3, z,
                                                   W1f, W1hf, W2f, W3f,
                                                   dWt1, dWt2, dWt3, zbf);
  ode_kernel<<<dim3(32), dim3(512), 0, stream>>>(z, W1f, W1hf, W2f, W3f, oW1,
                                                 ob1, ob2, ob3, times, vhist);
  dec_kernel<<<dim3(1600), dim3(512), 0, stream>>>(x, zbf, vhist, rank,
                                                   dWt1, dWt2, dWt3, db1, db2, db3,
                                                   (float*)d_out);
}

// Round 4
// 2955.843 us; speedup vs baseline: 4.4014x; 1.9249x over previous
//
#include <hip/hip_runtime.h>

// AbstractODEDecoder: unique-time grid + RK2(midpoint) latent ODE + fused MLP decoder.
// B=512, N=200, ZD=256, LD=128, HD=512, T=100, K=101.

typedef unsigned short u16;
typedef float f32x4 __attribute__((ext_vector_type(4)));
typedef short bf16x8 __attribute__((ext_vector_type(8)));
typedef u16 u16x8 __attribute__((ext_vector_type(8)));

#define MFMA16(a, b, c) __builtin_amdgcn_mfma_f32_16x16x32_bf16((a), (b), (c), 0, 0, 0)

constexpr int CB = 512;
constexpr int CN = 200;
constexpr int CZD = 256;
constexpr int CLD = 128;
constexpr int CHD = 512;
constexpr int CK = 101;
constexpr int CSTEPS = 100;

__device__ __forceinline__ u16 f2bf(float f) {
  unsigned u = __builtin_bit_cast(unsigned, f);
  u = (u + 0x7FFFu + ((u >> 16) & 1u)) >> 16;  // round-to-nearest-even bf16
  return (u16)u;
}

__device__ __forceinline__ f32x4 splat4(float v) {
  f32x4 r; r[0] = v; r[1] = v; r[2] = v; r[3] = v; return r;
}

__device__ __forceinline__ float fast_tanh(float x) {
  float e = __expf(2.0f * x);
  return 1.0f - 2.0f / (e + 1.0f);
}

// ---------------------------------------------------------------------------
// Kernel 1: unique-time grid (presence bitmap -> sorted times + rank)
// ---------------------------------------------------------------------------
__global__ void build_times_kernel(const float* __restrict__ x, const float* __restrict__ t0p,
                                   float* __restrict__ times, int* __restrict__ rank) {
  __shared__ int pres[128];
  const int tid = threadIdx.x;
  if (tid < 128) pres[tid] = 0;
  __syncthreads();
  for (int i = tid; i < CB * CN; i += blockDim.x) {
    float v = x[i];
    int gi = (int)(v * 100.0f + 0.5f);
    gi = gi < 0 ? 0 : (gi > 100 ? 100 : gi);
    pres[gi] = 1;
  }
  if (tid == 0) {
    float t0 = t0p[0];
    int gi = (int)(t0 * 100.0f + 0.5f);
    gi = gi < 0 ? 0 : (gi > 100 ? 100 : gi);
    pres[gi] = 1;
  }
  __syncthreads();
  if (tid == 0) {
    int c = 0;
    for (int i = 0; i <= 100; i++) {
      if (pres[i]) { times[c] = (float)i / 100.0f; rank[i] = c; c++; }
      else rank[i] = -1;
    }
    for (int j = c; j < CK; j++) times[j] = 1.0f;  // fill_value=1.0
  }
}

// ---------------------------------------------------------------------------
// Kernel 2: weight prep.
// ODE weights in fragment-linear bf16 layout: element ((c*NT + tile)*64 + lane)*8 + j
//   holds W[k = c*32 + (lane>>4)*8 + j][n = tile*16 + (lane&15)].
//   W1f: ode_W1 rows 0..127 (evolving latent). W1hf: rows 128..255 (z_hi, for c_pre).
//   W2f: 16 chunks x 32 tiles. W3f: 16 chunks x 8 tiles (128 cols).
// Decoder weights keep the round-1 [n][k] layout (dWt1 K-order: latent|z_hi|x).
// ---------------------------------------------------------------------------
__global__ void prep_kernel(
    const float* __restrict__ oW1, const float* __restrict__ oW2, const float* __restrict__ oW3,
    const float* __restrict__ dW1, const float* __restrict__ dW2, const float* __restrict__ dW3,
    const float* __restrict__ z,
    u16* __restrict__ W1f, u16* __restrict__ W1hf, u16* __restrict__ W2f, u16* __restrict__ W3f,
    u16* __restrict__ dWt1, u16* __restrict__ dWt2, u16* __restrict__ dWt3,
    u16* __restrict__ zbf) {
  const int tid = blockIdx.x * blockDim.x + threadIdx.x;
  const int nth = gridDim.x * blockDim.x;
  // W1f / W1hf: 4 chunks x 32 tiles
  for (int i = tid; i < 65536; i += nth) {
    int j = i & 7, lane = (i >> 3) & 63, tc = i >> 9, tile = tc & 31, c = tc >> 5;
    int k = c * 32 + (lane >> 4) * 8 + j, n = tile * 16 + (lane & 15);
    W1f[i]  = f2bf(oW1[k * 512 + n]);
    W1hf[i] = f2bf(oW1[(128 + k) * 512 + n]);
  }
  // W2f: 16 chunks x 32 tiles
  for (int i = tid; i < 262144; i += nth) {
    int j = i & 7, lane = (i >> 3) & 63, tc = i >> 9, tile = tc & 31, c = tc >> 5;
    int k = c * 32 + (lane >> 4) * 8 + j, n = tile * 16 + (lane & 15);
    W2f[i] = f2bf(oW2[k * 512 + n]);
  }
  // W3f: 16 chunks x 8 tiles
  for (int i = tid; i < 65536; i += nth) {
    int j = i & 7, lane = (i >> 3) & 63, tc = i >> 9, tile = tc & 7, c = tc >> 3;
    int k = c * 32 + (lane >> 4) * 8 + j, n = tile * 16 + (lane & 15);
    W3f[i] = f2bf(oW3[k * 128 + n]);
  }
  // decoder weights (round-1 layouts, verified)
  for (int i = tid; i < 512 * 288; i += nth) {
    int n = i / 288, k = i - n * 288;
    dWt1[i] = (k < 256) ? f2bf(dW1[(k + 1) * 512 + n])
                        : (k == 256 ? f2bf(dW1[n]) : (u16)0);
  }
  for (int i = tid; i < 512 * 512; i += nth) {
    int n = i >> 9, k = i & 511;
    dWt2[i] = f2bf(dW2[k * 512 + n]);
  }
  for (int i = tid; i < 512 * 512; i += nth) {
    int n = i >> 9, k = i & 511;
    dWt3[i] = f2bf(dW3[k * 512 + n]);
  }
  for (int i = tid; i < 512 * 128; i += nth) {
    int b = i >> 7, d = i & 127;
    zbf[i] = f2bf(z[b * 256 + 128 + d]);
  }
}

// ---------------------------------------------------------------------------
// Kernel 3: RK2(midpoint) ODE integrate. 32 blocks x 512 threads (8 waves),
// 16 rows/block. W1 in LDS; W3 resident in VGPRs (64); W2 streamed from L2
// via 6-deep statically-indexed register ring (96 VGPRs). launch_bounds(512,1)
// lifts the VGPR cap to 512 (LDS already limits to 1 block/CU = 2 waves/SIMD)
// so nothing spills. z_hi folded into c_pre; t is an f32 rank-1 update. State
// in the L3 C-fragment layout -> RK math is pure registers.
// ---------------------------------------------------------------------------
__global__ __launch_bounds__(512, 1) void ode_kernel(
    const float* __restrict__ z,
    const u16* __restrict__ W1f, const u16* __restrict__ W1hf,
    const u16* __restrict__ W2f, const u16* __restrict__ W3f,
    const float* __restrict__ oW1,
    const float* __restrict__ b1, const float* __restrict__ b2, const float* __restrict__ b3,
    const float* __restrict__ times, float* __restrict__ vhist) {
  __shared__ __align__(16) u16 W1L[4 * 32 * 64 * 8];  // 128 KiB, layout == W1f
  __shared__ __align__(16) u16 aF[4][64][8];          // A fragments (K=128), 4 KiB
  __shared__ __align__(16) u16 hF[16][64][8];         // h1/h2 time-shared, 16 KiB
  __shared__ float ts[104];

  const int tid = threadIdx.x, lane = tid & 63, wave = tid >> 6;
  const int colq = lane & 15, gq = lane >> 4;
  const int r0 = blockIdx.x * 16;
  const int d_ = wave * 16 + colq;  // state column this thread owns

  // stage W1 into LDS
  for (int i = tid; i < 8192; i += 512)
    *(u16x8*)&W1L[i * 8] = *(const u16x8*)&W1f[i * 8];
  if (tid < CK) ts[tid] = times[tid];

  // resident W3 fragments (64 VGPRs)
  bf16x8 w3f[16];
#pragma unroll
  for (int c = 0; c < 16; c++)
    w3f[c] = *(const bf16x8*)&W3f[((c * 8 + wave) * 64 + lane) * 8];

  float b2v[4], wtv[4];
#pragma unroll
  for (int t = 0; t < 4; t++) {
    int col = wave * 64 + t * 16 + colq;
    b2v[t] = b2[col];
    wtv[t] = oW1[256 * 512 + col];  // t-row of ode_W1
  }
  const float b3v = b3[d_];

  // state + vhist[0]
  f32x4 v;
#pragma unroll
  for (int r = 0; r < 4; r++) {
    v[r] = z[(r0 + gq * 4 + r) * CZD + d_];
    vhist[(0 * CB + r0 + gq * 4 + r) * CLD + d_] = v[r];
  }

  // --- c_pre = b1 + z_hi @ W1[128:256]  (constant across all evals) ---
  {
    int c = d_ >> 5, gh = (d_ & 31) >> 3, sl = d_ & 7;
#pragma unroll
    for (int r = 0; r < 4; r++)
      aF[c][gq * 4 + r + gh * 16][sl] = f2bf(z[(r0 + gq * 4 + r) * CZD + 128 + d_]);
  }
  __syncthreads();
  f32x4 cpre[4];
#pragma unroll
  for (int t = 0; t < 4; t++) cpre[t] = splat4(b1[wave * 64 + t * 16 + colq]);
#pragma unroll
  for (int c = 0; c < 4; c++) {
    bf16x8 af = *(const bf16x8*)&aF[c][lane][0];
#pragma unroll
    for (int t = 0; t < 4; t++)
      cpre[t] = MFMA16(af, *(const bf16x8*)&W1hf[((c * 32 + wave * 4 + t) * 64 + lane) * 8],
                       cpre[t]);
  }
  __syncthreads();  // aF reads done before first eval overwrites it

  auto eval = [&](f32x4 si, float tstage) -> f32x4 {
    // W2 stream ring: 6-deep, statically indexed (c-loop fully unrolled).
    // Prologue: issue chunks 0..5 now; they drain at bar1 / under L1.
    bf16x8 sb[6][4];
#pragma unroll
    for (int c0 = 0; c0 < 6; c0++)
#pragma unroll
      for (int t = 0; t < 4; t++)
        sb[c0][t] = *(const bf16x8*)&W2f[((c0 * 32 + wave * 4 + t) * 64 + lane) * 8];

    // write evolving-latent A fragments
    {
      int c = d_ >> 5, gh = (d_ & 31) >> 3, sl = d_ & 7;
#pragma unroll
      for (int r = 0; r < 4; r++)
        aF[c][gq * 4 + r + gh * 16][sl] = f2bf(si[r]);
    }
    __syncthreads();  // bar1: A ready (also fences prev-eval hF readers)

    // ---- L1: h1 = tanh(cpre + t*wt + vL @ W1)  (W1 from LDS) ----
    f32x4 acc[4];
#pragma unroll
    for (int t = 0; t < 4; t++) {
      f32x4 a;
#pragma unroll
      for (int r = 0; r < 4; r++) a[r] = cpre[t][r] + tstage * wtv[t];
      acc[t] = a;
    }
#pragma unroll
    for (int c = 0; c < 4; c++) {
      bf16x8 af = *(const bf16x8*)&aF[c][lane][0];
#pragma unroll
      for (int t = 0; t < 4; t++)
        acc[t] = MFMA16(af, *(const bf16x8*)&W1L[((c * 32 + wave * 4 + t) * 64 + lane) * 8],
                        acc[t]);
    }
#pragma unroll
    for (int t = 0; t < 4; t++) {
      int col = wave * 64 + t * 16 + colq;
      int cc = col >> 5, gh = (col & 31) >> 3, sl = col & 7;
#pragma unroll
      for (int r = 0; r < 4; r++)
        hF[cc][gq * 4 + r + gh * 16][sl] = f2bf(fast_tanh(acc[t][r]));
    }
    __syncthreads();  // bar2: h1 ready

    // ---- L2: h2 = tanh(h1 @ W2 + b2); 16 chunks streamed, 6-deep ring ----
#pragma unroll
    for (int t = 0; t < 4; t++) acc[t] = splat4(b2v[t]);
#pragma unroll
    for (int c = 0; c < 16; c++) {
      bf16x8 hf = *(const bf16x8*)&hF[c][lane][0];
#pragma unroll
      for (int t = 0; t < 4; t++) acc[t] = MFMA16(hf, sb[c % 6][t], acc[t]);
      if (c + 6 < 16) {
#pragma unroll
        for (int t = 0; t < 4; t++)
          sb[c % 6][t] =
              *(const bf16x8*)&W2f[(((c + 6) * 32 + wave * 4 + t) * 64 + lane) * 8];
      }
    }
    __syncthreads();  // bar3: all h1 reads done, safe to overwrite hF
#pragma unroll
    for (int t = 0; t < 4; t++) {
      int col = wave * 64 + t * 16 + colq;
      int cc = col >> 5, gh = (col & 31) >> 3, sl = col & 7;
#pragma unroll
      for (int r = 0; r < 4; r++)
        hF[cc][gq * 4 + r + gh * 16][sl] = f2bf(fast_tanh(acc[t][r]));
    }
    __syncthreads();  // bar4: h2 ready

    // ---- L3: dL = h2 @ W3 + b3 (resident W3; result lands in this thread's
    //      registers because C-fragment layout == state ownership) ----
    f32x4 a3 = splat4(b3v);
#pragma unroll
    for (int c = 0; c < 16; c++) {
      bf16x8 hf = *(const bf16x8*)&hF[c][lane][0];
      a3 = MFMA16(hf, w3f[c], a3);
    }
    return a3;
  };

#pragma unroll 1
  for (int s = 0; s < CSTEPS; s++) {
    const float t0s = ts[s], t1s = ts[s + 1];
    const float dt = t1s - t0s;

    // RK2 midpoint: v' = v + dt * f(t0 + dt/2, v + dt/2 * f(t0, v))
    f32x4 k1 = eval(v, t0s);
    f32x4 st;
#pragma unroll
    for (int r = 0; r < 4; r++) st[r] = v[r] + 0.5f * dt * k1[r];
    f32x4 k2 = eval(st, t0s + 0.5f * dt);
#pragma unroll
    for (int r = 0; r < 4; r++) v[r] += dt * k2[r];

#pragma unroll
    for (int r = 0; r < 4; r++)
      vhist[((s + 1) * CB + r0 + gq * 4 + r) * CLD + d_] = v[r];
  }
}

// ---------------------------------------------------------------------------
// Kernel 4: fused decoder (unchanged — verified). 1600 blocks x 512 threads,
// 64 rows/block; latent gather fused into A-tile build.
// ---------------------------------------------------------------------------
__global__ __launch_bounds__(512) void dec_kernel(
    const float* __restrict__ x, const u16* __restrict__ zbf,
    const float* __restrict__ vhist, const int* __restrict__ rank,
    const u16* __restrict__ Wt1, const u16* __restrict__ Wt2, const u16* __restrict__ Wt3,
    const float* __restrict__ b1, const float* __restrict__ b2, const float* __restrict__ b3,
    float* __restrict__ out) {
  __shared__ __align__(16) u16 hA[4][16][64][8];   // A (chunks 0..8), then h2
  __shared__ __align__(16) u16 h1F[4][16][64][8];  // h1
  __shared__ int rk[104];

  const int tid = threadIdx.x, lane = tid & 63, wave = tid >> 6;
  const int R0 = blockIdx.x * 64;

  if (tid < CK) rk[tid] = rank[tid];
  __syncthreads();

  {  // build A-tile (fused latent gather)
    const int i = tid >> 3, j = tid & 7;
    const int row = R0 + i;
    const int b = row / CN;
    const float xv = x[row];
    int gi = (int)(xv * 100.0f + 0.5f);
    gi = gi < 0 ? 0 : (gi > 100 ? 100 : gi);
    const int k = rk[gi];
    const int mt = i >> 4, m = i & 15;
    const float4* lp = (const float4*)&vhist[((k * CB) + b) * CLD + j * 16];
    float4 l0 = lp[0], l1 = lp[1], l2 = lp[2], l3 = lp[3];
    u16x8 lv0, lv1;
    lv0[0] = f2bf(l0.x); lv0[1] = f2bf(l0.y); lv0[2] = f2bf(l0.z); lv0[3] = f2bf(l0.w);
    lv0[4] = f2bf(l1.x); lv0[5] = f2bf(l1.y); lv0[6] = f2bf(l1.z); lv0[7] = f2bf(l1.w);
    lv1[0] = f2bf(l2.x); lv1[1] = f2bf(l2.y); lv1[2] = f2bf(l2.z); lv1[3] = f2bf(l2.w);
    lv1[4] = f2bf(l3.x); lv1[5] = f2bf(l3.y); lv1[6] = f2bf(l3.z); lv1[7] = f2bf(l3.w);
    const int c = j >> 1, gh = (j & 1) * 2;
    *(u16x8*)&hA[mt][c][m + gh * 16][0] = lv0;
    *(u16x8*)&hA[mt][c][m + (gh + 1) * 16][0] = lv1;
    const u16x8* zp = (const u16x8*)&zbf[b * CLD + j * 16];
    u16x8 zv0 = zp[0], zv1 = zp[1];
    *(u16x8*)&hA[mt][4 + c][m + gh * 16][0] = zv0;
    *(u16x8*)&hA[mt][4 + c][m + (gh + 1) * 16][0] = zv1;
    if (j == 0) {
      hA[mt][8][m][0] = f2bf(xv);
#pragma unroll
      for (int q = 1; q < 8; q++) hA[mt][8][m][q] = 0;
    } else if (j < 4) {
      u16x8 zz = {0, 0, 0, 0, 0, 0, 0, 0};
      *(u16x8*)&hA[mt][8][m + j * 16][0] = zz;
    }
  }
  __syncthreads();

  const int colq = lane & 15, gq = lane >> 4;
  const int nb = wave * 64;
  f32x4 acc[4][4];

  // ---- L1 ----
#pragma unroll
  for (int nt = 0; nt < 4; nt++) {
    float bv = b1[nb + nt * 16 + colq];
#pragma unroll
    for (int mt = 0; mt < 4; mt++) acc[mt][nt] = splat4(bv);
  }
#pragma unroll
  for (int c = 0; c < 9; c++) {
    bf16x8 af0 = *(const bf16x8*)&hA[0][c][lane][0];
    bf16x8 af1 = *(const bf16x8*)&hA[1][c][lane][0];
    bf16x8 af2 = *(const bf16x8*)&hA[2][c][lane][0];
    bf16x8 af3 = *(const bf16x8*)&hA[3][c][lane][0];
#pragma unroll
    for (int nt = 0; nt < 4; nt++) {
      bf16x8 bfv = *(const bf16x8*)&Wt1[(size_t)(nb + nt * 16 + colq) * 288 + c * 32 + gq * 8];
      acc[0][nt] = MFMA16(af0, bfv, acc[0][nt]);
      acc[1][nt] = MFMA16(af1, bfv, acc[1][nt]);
      acc[2][nt] = MFMA16(af2, bfv, acc[2][nt]);
      acc[3][nt] = MFMA16(af3, bfv, acc[3][nt]);
    }
  }
#pragma unroll
  for (int mt = 0; mt < 4; mt++)
#pragma unroll
    for (int nt = 0; nt < 4; nt++) {
      int col = nb + nt * 16 + colq;
      int cc = col >> 5, gh = (col & 31) >> 3, sl = col & 7;
#pragma unroll
      for (int r = 0; r < 4; r++)
        h1F[mt][cc][gq * 4 + r + gh * 16][sl] = f2bf(fmaxf(acc[mt][nt][r], 0.0f));
    }
  __syncthreads();

  // ---- L2 ----
#pragma unroll
  for (int nt = 0; nt < 4; nt++) {
    float bv = b2[nb + nt * 16 + colq];
#pragma unroll
    for (int mt = 0; mt < 4; mt++) acc[mt][nt] = splat4(bv);
  }
#pragma unroll
  for (int c = 0; c < 16; c++) {
    bf16x8 af0 = *(const bf16x8*)&h1F[0][c][lane][0];
    bf16x8 af1 = *(const bf16x8*)&h1F[1][c][lane][0];
    bf16x8 af2 = *(const bf16x8*)&h1F[2][c][lane][0];
    bf16x8 af3 = *(const bf16x8*)&h1F[3][c][lane][0];
#pragma unroll
    for (int nt = 0; nt < 4; nt++) {
      bf16x8 bfv = *(const bf16x8*)&Wt2[(size_t)(nb + nt * 16 + colq) * 512 + c * 32 + gq * 8];
      acc[0][nt] = MFMA16(af0, bfv, acc[0][nt]);
      acc[1][nt] = MFMA16(af1, bfv, acc[1][nt]);
      acc[2][nt] = MFMA16(af2, bfv, acc[2][nt]);
      acc[3][nt] = MFMA16(af3, bfv, acc[3][nt]);
    }
  }
#pragma unroll
  for (int mt = 0; mt < 4; mt++)
#pragma unroll
    for (int nt = 0; nt < 4; nt++) {
      int col = nb + nt * 16 + colq;
      int cc = col >> 5, gh = (col & 31) >> 3, sl = col & 7;
#pragma unroll
      for (int r = 0; r < 4; r++)
        hA[mt][cc][gq * 4 + r + gh * 16][sl] = f2bf(fmaxf(acc[mt][nt][r], 0.0f));
    }
  __syncthreads();

  // ---- L3 ----
#pragma unroll
  for (int nt = 0; nt < 4; nt++) {
    float bv = b3[nb + nt * 16 + colq];
#pragma unroll
    for (int mt = 0; mt < 4; mt++) acc[mt][nt] = splat4(bv);
  }
#pragma unroll
  for (int c = 0; c < 16; c++) {
    bf16x8 af0 = *(const bf16x8*)&hA[0][c][lane][0];
    bf16x8 af1 = *(const bf16x8*)&hA[1][c][lane][0];
    bf16x8 af2 = *(const bf16x8*)&hA[2][c][lane][0];
    bf16x8 af3 = *(const bf16x8*)&hA[3][c][lane][0];
#pragma unroll
    for (int nt = 0; nt < 4; nt++) {
      bf16x8 bfv = *(const bf16x8*)&Wt3[(size_t)(nb + nt * 16 + colq) * 512 + c * 32 + gq * 8];
      acc[0][nt] = MFMA16(af0, bfv, acc[0][nt]);
      acc[1][nt] = MFMA16(af1, bfv, acc[1][nt]);
      acc[2][nt] = MFMA16(af2, bfv, acc[2][nt]);
      acc[3][nt] = MFMA16(af3, bfv, acc[3][nt]);
    }
  }
#pragma unroll
  for (int mt = 0; mt < 4; mt++)
#pragma unroll
    for (int nt = 0; nt < 4; nt++) {
      int col = nb + nt * 16 + colq;
#pragma unroll
      for (int r = 0; r < 4; r++) {
        int row = R0 + mt * 16 + gq * 4 + r;
        out[(size_t)row * CHD + col] = fmaxf(acc[mt][nt][r], 0.0f);
      }
    }
}

// ---------------------------------------------------------------------------
extern "C" void kernel_launch(void* const* d_in, const int* in_sizes, int n_in,
                              void* d_out, int out_size, void* d_ws, size_t ws_size,
                              hipStream_t stream) {
  (void)in_sizes; (void)n_in; (void)out_size; (void)ws_size;

  const float* x   = (const float*)d_in[0];
  const float* z   = (const float*)d_in[1];
  const float* t0  = (const float*)d_in[2];
  const float* oW1 = (const float*)d_in[3];
  const float* ob1 = (const float*)d_in[4];
  const float* oW2 = (const float*)d_in[5];
  const float* ob2 = (const float*)d_in[6];
  const float* oW3 = (const float*)d_in[7];
  const float* ob3 = (const float*)d_in[8];
  const float* dW1 = (const float*)d_in[9];
  const float* db1 = (const float*)d_in[10];
  const float* dW2 = (const float*)d_in[11];
  const float* db2 = (const float*)d_in[12];
  const float* dW3 = (const float*)d_in[13];
  const float* db3 = (const float*)d_in[14];

  char* ws = (char*)d_ws;
  size_t off = 0;
  auto alloc = [&](size_t bytes) {
    void* p = ws + off;
    off = (off + bytes + 255) & ~(size_t)255;
    return p;
  };
  float* vhist = (float*)alloc((size_t)CK * CB * CLD * 4);  // 26.5 MB
  u16* W1f  = (u16*)alloc(65536 * 2);
  u16* W1hf = (u16*)alloc(65536 * 2);
  u16* W2f  = (u16*)alloc(262144 * 2);
  u16* W3f  = (u16*)alloc(65536 * 2);
  u16* dWt1 = (u16*)alloc(512 * 288 * 2);
  u16* dWt2 = (u16*)alloc(512 * 512 * 2);
  u16* dWt3 = (u16*)alloc(512 * 512 * 2);
  u16* zbf  = (u16*)alloc(512 * 128 * 2);
  float* times = (float*)alloc(512);
  int* rank    = (int*)alloc(512);

  build_times_kernel<<<dim3(1), dim3(256), 0, stream>>>(x, t0, times, rank);
  prep_kernel<<<dim3(512), dim3(256), 0, stream>>>(oW1, oW2, oW3, dW1, dW2, dW3, z,
                                                   W1f, W1hf, W2f, W3f,
                                                   dWt1, dWt2, dWt3, zbf);
  ode_kernel<<<dim3(32), dim3(512), 0, stream>>>(z, W1f, W1hf, W2f, W3f, oW1,
                                                 ob1, ob2, ob3, times, vhist);
  dec_kernel<<<dim3(1600), dim3(512), 0, stream>>>(x, zbf, vhist, rank,
                                                   dWt1, dWt2, dWt3, db1, db2, db3,
                                                   (float*)d_out);
}